// Round 9
// baseline (374.171 us; speedup 1.0000x reference)
//
#include <hip/hip_runtime.h>
#include <hip/hip_cooperative_groups.h>
#include <math.h>

#define B_    2
#define S_    512
#define HDIM  1024
#define D_    24      // proj dim
#define M_    96      // pair-MLP hidden
#define ROWS  (B_*S_) // 1024

typedef _Float16 half8 __attribute__((ext_vector_type(8)));
typedef float    f32x4 __attribute__((ext_vector_type(4)));
typedef unsigned short ushort8 __attribute__((ext_vector_type(8)));

namespace cg = cooperative_groups;

struct KArgs {
  const float *Hj, *Hi, *mask, *pj, *pi, *W1, *b1, *W2, *bv1, *Wv1, *Wv2, *bv2, *alpha;
  _Float16 *HjH, *HiT, *Wv1T, *Wv2T, *Wimg, *probsH, *ctxH, *hidH;
  float *Zj, *Zi, *out;
};

// ---------------------------------------------------------------------------
// cache-based 64x64 fp32->fp16 transpose, 512 threads, no LDS
// ---------------------------------------------------------------------------
__device__ __forceinline__ void transpose_tile64_512(
    const float* __restrict__ in, _Float16* __restrict__ out,
    int R, int C, int xt, int yt, int t) {
  int R0 = yt * 64, C0 = xt * 64;
  int c = t >> 3, rq = (t & 7) * 8;
  _Float16 o[8];
  const float* src = in + (size_t)(R0 + rq) * C + C0 + c;
#pragma unroll
  for (int e = 0; e < 8; ++e) o[e] = (_Float16)src[(size_t)e * C];
  *(ushort8*)(out + (size_t)(C0 + c) * R + R0 + rq) = *(ushort8*)o;
}

// ---------------------------------------------------------------------------
// Wimg build, 512 threads (fp16 subtiled image of W1 rows 24..95 + zero pad)
// ---------------------------------------------------------------------------
__device__ __forceinline__ void wimg_512(
    const float* __restrict__ W1, _Float16* __restrict__ Wimg, int t) {
#pragma unroll
  for (int q = 0; q < 2; ++q) {
    int c = t + q * 512;   // 0..1023
    half8 v = {};
    if (c < 864) {
      int kc = c / 96, m = c - kc * 96;
#pragma unroll
      for (int e = 0; e < 8; ++e)
        v[e] = (_Float16)W1[(24 + kc * 8 + e) * M_ + m];
    }
    *(half8*)(Wimg + (size_t)c * 8) = v;
  }
}

// ---------------------------------------------------------------------------
// MFMA projection, 128 rows per task (8 waves x 16 rows), 512 threads.
// P staged into LDS fp16 B-fragments in two 16-step phases (32KB).
// ---------------------------------------------------------------------------
template <bool EMITH>
__device__ __forceinline__ void proj_mfma128(
    const float* __restrict__ H, const float* __restrict__ P,
    float* __restrict__ Z, _Float16* __restrict__ Himg,
    int r0, char* smem, int t) {
  const int w = t >> 6, l = t & 63;
  const int lo = l & 15, hi = l >> 4;
  const int row = r0 + w * 16 + lo;
  const float* hrow = H + (size_t)row * HDIM;
  f32x4 acc0 = {}, acc1 = {};
  __syncthreads();   // smem free of previous task's readers

  for (int ph = 0; ph < 2; ++ph) {
    if (ph) __syncthreads();
    for (int q = 0; q < 4; ++q) {
      int s = t + q * 512;
      int slo = s & 15, shi = (s >> 4) & 3, snt = (s >> 6) & 1, sst = s >> 7;
      int d = snt * 16 + slo;
      half8 v = {};
      if (d < D_) {
        int k = (ph * 16 + sst) * 32 + shi * 8;
#pragma unroll
        for (int e = 0; e < 8; ++e)
          v[e] = (_Float16)P[(size_t)(k + e) * D_ + d];
      }
      *(half8*)(smem + s * 16) = v;
    }
    __syncthreads();

    for (int st = 0; st < 16; ++st) {
      int step = ph * 16 + st;
      const float* src = hrow + step * 32 + hi * 8;
      float4 v0 = *(const float4*)src;
      float4 v1 = *(const float4*)(src + 4);
      half8 a8;
      a8[0] = (_Float16)v0.x; a8[1] = (_Float16)v0.y;
      a8[2] = (_Float16)v0.z; a8[3] = (_Float16)v0.w;
      a8[4] = (_Float16)v1.x; a8[5] = (_Float16)v1.y;
      a8[6] = (_Float16)v1.z; a8[7] = (_Float16)v1.w;
      if (EMITH)
        *(half8*)(Himg + (size_t)row * HDIM + step * 32 + hi * 8) = a8;
      half8 b0 = *(const half8*)(smem + ((st * 2 + 0) * 64 + l) * 16);
      half8 b1 = *(const half8*)(smem + ((st * 2 + 1) * 64 + l) * 16);
      acc0 = __builtin_amdgcn_mfma_f32_16x16x32_f16(a8, b0, acc0, 0, 0, 0);
      acc1 = __builtin_amdgcn_mfma_f32_16x16x32_f16(a8, b1, acc1, 0, 0, 0);
    }
  }
#pragma unroll
  for (int rg = 0; rg < 4; ++rg) {
    int zr = r0 + w * 16 + hi * 4 + rg;
    Z[(size_t)zr * D_ + lo] = acc0[rg];
    if (lo < 8) Z[(size_t)zr * D_ + 16 + lo] = acc1[rg];
  }
}

// ---------------------------------------------------------------------------
// prep task dispatch (1041 tasks), 512 threads each
// ---------------------------------------------------------------------------
__device__ __forceinline__ void prep_task(const KArgs& a, int task, char* smem, int t) {
  if (task < 8) {
    proj_mfma128<true>(a.Hj, a.pj, a.Zj, a.HjH, task * 128, smem, t);
  } else if (task < 16) {
    proj_mfma128<false>(a.Hi, a.pi, a.Zi, nullptr, (task - 8) * 128, smem, t);
  } else if (task == 16) {
    wimg_512(a.W1, a.Wimg, t);
  } else if (task < 273) {
    int id = task - 17;
    int z = id >> 7, rem = id & 127;
    transpose_tile64_512(a.Hi + (size_t)z * S_ * HDIM,
                         a.HiT + (size_t)z * HDIM * S_,
                         S_, HDIM, rem & 15, rem >> 4, t);
  } else if (task < 785) {
    int id = task - 273;
    transpose_tile64_512(a.Wv1, a.Wv1T, 2 * HDIM, HDIM, id & 15, id >> 4, t);
  } else {
    int id = task - 785;
    transpose_tile64_512(a.Wv2, a.Wv2T, HDIM, HDIM, id & 15, id >> 4, t);
  }
}

// ---------------------------------------------------------------------------
// Fused pair-MLP + softmax for ONE j-row on a 256-thread half (tl = t&255).
// Both halves of a 512-thr block run this symmetrically (equal barrier count).
// ---------------------------------------------------------------------------
#define FOFFB   0                       // 10*256*16 = 40960
#define WOFFB   40960                   // 1024 chunks * 16 = 16384
#define ZOFFB   (WOFFB + 960*16)        // zero chunk
#define LOGOFFB (WOFFB + 16384)         // 512 f32 logits
#define ZJOFFB  (LOGOFFB + 2048)        // 24 f32
#define W2OFFB  (ZJOFFB + 96)           // 96 f32
#define REDOFFB (W2OFFB + 384)          // 8 f32
#define PAIRLDS 61440                   // per-half region (>= 59904)

__device__ __forceinline__ void pair_half(
    const float* __restrict__ Zj, const float* __restrict__ Zi,
    const float* __restrict__ W1, const float* __restrict__ b1,
    const float* __restrict__ W2, const _Float16* __restrict__ Wimg,
    const float* __restrict__ mask, _Float16* __restrict__ probs,
    int rj, char* smem, int tl) {
  const int wl = tl >> 6, l = tl & 63;
  const int lo = l & 15, hi = l >> 4;
  const int b = rj >> 9;

  __syncthreads();   // smem free of previous users
#pragma unroll
  for (int r = 0; r < 4; ++r) {
    const _Float16* src = Wimg + (size_t)(r * 256 + wl * 64 + l) * 8;
    __builtin_amdgcn_global_load_lds(
        (const __attribute__((address_space(1))) void*)src,
        (__attribute__((address_space(3))) void*)(smem + WOFFB + (r * 256 + wl * 64) * 16),
        16, 0, 0);
  }
  float* zjL    = (float*)(smem + ZJOFFB);
  float* W2s    = (float*)(smem + W2OFFB);
  float* logits = (float*)(smem + LOGOFFB);
  float* red    = (float*)(smem + REDOFFB);
  if (tl < D_) zjL[tl] = Zj[(size_t)rj * D_ + tl];
  if (tl < M_) W2s[tl] = W2[tl];
  float aj = 0.f;
  if (tl < M_) {
    aj = b1[tl];
#pragma unroll
    for (int d = 0; d < D_; ++d)
      aj = fmaf(Zj[(size_t)rj * D_ + d], W1[d * M_ + tl], aj);
  }
  __syncthreads();
  if (tl < M_) {
    half8 v = {};
    v[0] = (_Float16)aj;
    *(half8*)(smem + WOFFB + (864 + tl) * 16) = v;  // Aj row at K=72
  }

  half8 wf[6][3];
  float w2r[6][4];

  for (int p = 0; p < 2; ++p) {
    {
      int i = p * 256 + tl;
      const float* zi = Zi + (size_t)(b * S_ + i) * D_;
      float ziv[D_];
#pragma unroll
      for (int q = 0; q < 6; ++q) {
        float4 v = ((const float4*)zi)[q];
        ziv[q * 4 + 0] = v.x; ziv[q * 4 + 1] = v.y;
        ziv[q * 4 + 2] = v.z; ziv[q * 4 + 3] = v.w;
      }
#pragma unroll
      for (int kc = 0; kc < 3; ++kc) {
        half8 v;
#pragma unroll
        for (int e = 0; e < 8; ++e) v[e] = (_Float16)ziv[kc * 8 + e];
        *(half8*)(smem + FOFFB + (kc * 256 + tl) * 16) = v;
      }
#pragma unroll
      for (int kc = 0; kc < 3; ++kc) {
        half8 v;
#pragma unroll
        for (int e = 0; e < 8; ++e) {
          int d = kc * 8 + e;
          v[e] = (_Float16)(zjL[d] * ziv[d]);
        }
        *(half8*)(smem + FOFFB + ((kc + 3) * 256 + tl) * 16) = v;
      }
#pragma unroll
      for (int kc = 0; kc < 3; ++kc) {
        half8 v;
#pragma unroll
        for (int e = 0; e < 8; ++e) {
          int d = kc * 8 + e;
          v[e] = (_Float16)fabsf(zjL[d] - ziv[d]);
        }
        *(half8*)(smem + FOFFB + ((kc + 6) * 256 + tl) * 16) = v;
      }
      if (p == 0) {
        half8 v = {};
        v[0] = (_Float16)1.0f;
        *(half8*)(smem + FOFFB + (9 * 256 + tl) * 16) = v;
      }
    }
    __syncthreads();

    if (p == 0) {
#pragma unroll
      for (int mh = 0; mh < 6; ++mh) {
#pragma unroll
        for (int ks = 0; ks < 3; ++ks) {
          int kc = ks * 4 + hi;
          int off = (kc < 10) ? (WOFFB + (kc * 96 + mh * 16 + lo) * 16) : ZOFFB;
          wf[mh][ks] = *(const half8*)(smem + off);
        }
#pragma unroll
        for (int r = 0; r < 4; ++r) w2r[mh][r] = W2s[mh * 16 + hi * 4 + r];
      }
    }

#pragma unroll
    for (int nt = 0; nt < 4; ++nt) {
      half8 ff[3];
#pragma unroll
      for (int ks = 0; ks < 3; ++ks) {
        int kc = ks * 4 + hi;
        int off = (kc < 10) ? (FOFFB + (kc * 256 + wl * 64 + nt * 16 + lo) * 16) : ZOFFB;
        ff[ks] = *(const half8*)(smem + off);
      }
      f32x4 a6[6] = {};
      __builtin_amdgcn_s_setprio(1);
#pragma unroll
      for (int ks = 0; ks < 3; ++ks)
#pragma unroll
        for (int mh = 0; mh < 6; ++mh)
          a6[mh] = __builtin_amdgcn_mfma_f32_16x16x32_f16(wf[mh][ks], ff[ks], a6[mh], 0, 0, 0);
      __builtin_amdgcn_s_setprio(0);
      float part = 0.f;
#pragma unroll
      for (int mh = 0; mh < 6; ++mh)
#pragma unroll
        for (int r = 0; r < 4; ++r)
          part = fmaf(fmaxf(a6[mh][r], 0.f), w2r[mh][r], part);
      part += __shfl_xor(part, 16);
      part += __shfl_xor(part, 32);
      if (hi == 0) logits[p * 256 + wl * 64 + nt * 16 + lo] = part;
    }
    __syncthreads();
  }

  float m1 = mask[b * S_ + tl], m2 = mask[b * S_ + tl + 256];
  float lg1 = logits[tl]       + (1.0f - m1) * (-3.40282347e38f);
  float lg2 = logits[tl + 256] + (1.0f - m2) * (-3.40282347e38f);
  float mx = fmaxf(lg1, lg2);
#pragma unroll
  for (int off = 32; off > 0; off >>= 1) mx = fmaxf(mx, __shfl_xor(mx, off));
  if (l == 0) red[wl] = mx;
  __syncthreads();
  float rmax = fmaxf(fmaxf(red[0], red[1]), fmaxf(red[2], red[3]));
  float e1 = __expf(lg1 - rmax);
  float e2 = __expf(lg2 - rmax);
  float s = e1 + e2;
#pragma unroll
  for (int off = 32; off > 0; off >>= 1) s += __shfl_xor(s, off);
  if (l == 0) red[4 + wl] = s;
  __syncthreads();
  float inv = 1.0f / (red[4] + red[5] + red[6] + red[7]);
  probs[(size_t)rj * S_ + tl]       = (_Float16)(e1 * inv);
  probs[(size_t)rj * S_ + tl + 256] = (_Float16)(e2 * inv);
}

// ---------------------------------------------------------------------------
// fp16 MFMA GEMM tile, 512 thr = 2 groups x 4 waves, in-block split-K/2
// (proven r4 config), as device function.
// ---------------------------------------------------------------------------
template <bool HASA1, bool RELU, bool FINAL, bool OUTH>
__device__ __forceinline__ void gemm_tile(
    const _Float16* __restrict__ A0, const _Float16* __restrict__ A1,
    const _Float16* __restrict__ Bt, const float* __restrict__ bias,
    const float* __restrict__ alpha_ptr, void* __restrict__ Cout,
    int N, int K0, int K1, long aB0, long aB1, long bB, long cB,
    int n0, int m0, int zb, char* smem, int t) {
  const int w = t >> 6, l = t & 63;
  const int g = w >> 2, wq = w & 3;
  const int K = K0 + K1;
  const int KH = K >> 1;
  const int NT = KH >> 5;
  const _Float16* A0b = A0 + (size_t)zb * aB0;
  const _Float16* A1b = HASA1 ? (A1 + (size_t)zb * aB1) : nullptr;
  const _Float16* Btb = Bt + (size_t)zb * bB;
  char* gls = smem + (g << 15);

  const int sr = (wq << 4) + (l >> 2);
  const int sk = ((l & 3) ^ ((l >> 3) & 3)) << 3;

  const int mq = wq >> 1, nq = wq & 1;
  int offA[2], offB[2];
#pragma unroll
  for (int i = 0; i < 2; ++i) {
    int ra = mq * 32 + i * 16 + (l & 15);
    offA[i] = ra * 64 + (((l >> 4) ^ ((ra >> 1) & 3)) << 4);
    int rb = nq * 32 + i * 16 + (l & 15);
    offB[i] = 4096 + rb * 64 + (((l >> 4) ^ ((rb >> 1) & 3)) << 4);
  }

  f32x4 acc[2][2] = {};

  auto stage = [&](int tt) {
    char* buf = gls + (tt & 3) * 8192;
    int kg = g * KH + (tt << 5) + sk;
    const _Float16* ga;
    if (HASA1 && kg >= K0) ga = A1b + (size_t)(m0 + sr) * K1 + (kg - K0);
    else                   ga = A0b + (size_t)(m0 + sr) * K0 + kg;
    __builtin_amdgcn_global_load_lds(
        (const __attribute__((address_space(1))) void*)ga,
        (__attribute__((address_space(3))) void*)(buf + (wq << 10)), 16, 0, 0);
    const _Float16* gb = Btb + (size_t)(n0 + sr) * K + kg;
    __builtin_amdgcn_global_load_lds(
        (const __attribute__((address_space(1))) void*)gb,
        (__attribute__((address_space(3))) void*)(buf + 4096 + (wq << 10)), 16, 0, 0);
  };

  __syncthreads();   // smem free of previous users
  stage(0);
  stage(1);
  stage(2);

  for (int tt = 0; tt < NT; ++tt) {
    if (tt + 2 < NT)      asm volatile("s_waitcnt vmcnt(4)" ::: "memory");
    else if (tt + 1 < NT) asm volatile("s_waitcnt vmcnt(2)" ::: "memory");
    else                  asm volatile("s_waitcnt vmcnt(0)" ::: "memory");
    __builtin_amdgcn_s_barrier();
    __builtin_amdgcn_sched_barrier(0);
    const char* buf = gls + (tt & 3) * 8192;
    half8 a0 = *(const half8*)(buf + offA[0]);
    half8 a1 = *(const half8*)(buf + offA[1]);
    half8 b0 = *(const half8*)(buf + offB[0]);
    half8 b1v = *(const half8*)(buf + offB[1]);
    acc[0][0] = __builtin_amdgcn_mfma_f32_16x16x32_f16(a0, b0, acc[0][0], 0, 0, 0);
    acc[0][1] = __builtin_amdgcn_mfma_f32_16x16x32_f16(a0, b1v, acc[0][1], 0, 0, 0);
    acc[1][0] = __builtin_amdgcn_mfma_f32_16x16x32_f16(a1, b0, acc[1][0], 0, 0, 0);
    acc[1][1] = __builtin_amdgcn_mfma_f32_16x16x32_f16(a1, b1v, acc[1][1], 0, 0, 0);
    if (tt + 3 < NT) stage(tt + 3);
  }

  const int lr = l & 15, lq = l >> 4;
  float* redm = (float*)smem;   // [64][68]
  __syncthreads();
  if (g == 1) {
#pragma unroll
    for (int mi = 0; mi < 2; ++mi)
#pragma unroll
      for (int ni = 0; ni < 2; ++ni)
#pragma unroll
        for (int rg = 0; rg < 4; ++rg)
          redm[(mq * 32 + mi * 16 + lq * 4 + rg) * 68 + nq * 32 + ni * 16 + lr] =
              acc[mi][ni][rg];
  }
  __syncthreads();
  if (g == 0) {
    const float alpha = FINAL ? *alpha_ptr : 1.0f;
    const size_t cbase = (size_t)zb * cB;
#pragma unroll
    for (int mi = 0; mi < 2; ++mi)
#pragma unroll
      for (int ni = 0; ni < 2; ++ni) {
        int col = n0 + nq * 32 + ni * 16 + lr;
        float bv = bias ? bias[col] : 0.0f;
#pragma unroll
        for (int rg = 0; rg < 4; ++rg) {
          int row = m0 + mq * 32 + mi * 16 + lq * 4 + rg;
          float x = acc[mi][ni][rg] +
                    redm[(mq * 32 + mi * 16 + lq * 4 + rg) * 68 + nq * 32 + ni * 16 + lr] +
                    bv;
          if (RELU) x = fmaxf(x, 0.f);
          if (FINAL) x *= alpha;
          if (OUTH)
            ((_Float16*)Cout)[cbase + (size_t)row * N + col] = (_Float16)x;
          else
            ((float*)Cout)[cbase + (size_t)row * N + col] = x;
        }
      }
  }
}

// ---------------------------------------------------------------------------
// Cooperative mega-kernel: 256 blocks x 512 threads, 5 phases, grid syncs
// ---------------------------------------------------------------------------
__global__ __launch_bounds__(512, 2) void mega_kernel(KArgs a) {
  __shared__ __attribute__((aligned(16))) char smem[122880];
  const int t = threadIdx.x;
  const int bid = blockIdx.x;
  cg::grid_group grid = cg::this_grid();

  // Phase A: prep (proj MFMA, Wimg, transposes) — 1041 tasks grid-strided
  for (int task = bid; task < 1041; task += 256)
    prep_task(a, task, smem, t);
  __threadfence(); grid.sync();

  // Phase B: pair-MLP + softmax — 1024 rows, 2 per block per iter, 2 iters
  for (int it = 0; it < 2; ++it) {
    int rj = it * 512 + bid * 2 + (t >> 8);
    pair_half(a.Zj, a.Zi, a.W1, a.b1, a.W2, a.Wimg, a.mask, a.probsH,
              rj, smem + (t >> 8) * PAIRLDS, t & 255);
  }
  __threadfence(); grid.sync();

  // Phase C: ctx[b] = probs[b] @ Hi[b]  (256 tiles)
  gemm_tile<false, false, false, true>(
      a.probsH, nullptr, a.HiT, nullptr, nullptr, a.ctxH,
      HDIM, S_, 0, (long)S_ * S_, 0, (long)HDIM * S_, (long)S_ * HDIM,
      (bid & 15) * 64, ((bid >> 4) & 7) * 64, bid >> 7, smem, t);
  __threadfence(); grid.sync();

  // Phase D: hidden = relu([ctx|Hj] @ Wv1 + bv1)  (256 tiles)
  gemm_tile<true, true, false, true>(
      a.ctxH, a.HjH, a.Wv1T, a.bv1, nullptr, a.hidH,
      HDIM, HDIM, HDIM, 0, 0, 0, 0,
      (bid & 15) * 64, (bid >> 4) * 64, 0, smem, t);
  __threadfence(); grid.sync();

  // Phase E: out = alpha * (hidden @ Wv2 + bv2)  (256 tiles)
  gemm_tile<false, false, true, false>(
      a.hidH, nullptr, a.Wv2T, a.bv2, a.alpha, a.out,
      HDIM, HDIM, 0, 0, 0, 0, 0,
      (bid & 15) * 64, (bid >> 4) * 64, 0, smem, t);
}

// ---------------------------------------------------------------------------
// Fallback kernels (same device code, 5 plain launches)
// ---------------------------------------------------------------------------
__global__ __launch_bounds__(512) void fb_prep_kernel(KArgs a) {
  __shared__ __attribute__((aligned(16))) char smem[32768];
  prep_task(a, blockIdx.x, smem, threadIdx.x);
}

__global__ __launch_bounds__(512) void fb_pair_kernel(KArgs a) {
  __shared__ __attribute__((aligned(16))) char smem[2 * PAIRLDS];
  int t = threadIdx.x;
  int rj = blockIdx.x * 2 + (t >> 8);
  pair_half(a.Zj, a.Zi, a.W1, a.b1, a.W2, a.Wimg, a.mask, a.probsH,
            rj, smem + (t >> 8) * PAIRLDS, t & 255);
}

__global__ __launch_bounds__(512) void fb_gemm1_kernel(KArgs a) {
  __shared__ __attribute__((aligned(16))) char smem[65536];
  int bid = blockIdx.x;
  gemm_tile<false, false, false, true>(
      a.probsH, nullptr, a.HiT, nullptr, nullptr, a.ctxH,
      HDIM, S_, 0, (long)S_ * S_, 0, (long)HDIM * S_, (long)S_ * HDIM,
      (bid & 15) * 64, ((bid >> 4) & 7) * 64, bid >> 7, smem, threadIdx.x);
}

__global__ __launch_bounds__(512) void fb_gemm2_kernel(KArgs a) {
  __shared__ __attribute__((aligned(16))) char smem[65536];
  int bid = blockIdx.x;
  gemm_tile<true, true, false, true>(
      a.ctxH, a.HjH, a.Wv1T, a.bv1, nullptr, a.hidH,
      HDIM, HDIM, HDIM, 0, 0, 0, 0,
      (bid & 15) * 64, (bid >> 4) * 64, 0, smem, threadIdx.x);
}

__global__ __launch_bounds__(512) void fb_gemm3_kernel(KArgs a) {
  __shared__ __attribute__((aligned(16))) char smem[65536];
  int bid = blockIdx.x;
  gemm_tile<false, false, true, false>(
      a.hidH, nullptr, a.Wv2T, a.bv2, a.alpha, a.out,
      HDIM, HDIM, 0, 0, 0, 0, 0,
      (bid & 15) * 64, (bid >> 4) * 64, 0, smem, threadIdx.x);
}

// ---------------------------------------------------------------------------
extern "C" void kernel_launch(void* const* d_in, const int* in_sizes, int n_in,
                              void* d_out, int out_size, void* d_ws, size_t ws_size,
                              hipStream_t stream) {
  KArgs a;
  a.Hj   = (const float*)d_in[0];
  a.Hi   = (const float*)d_in[1];
  a.mask = (const float*)d_in[2];
  a.pj   = (const float*)d_in[3];
  a.pi   = (const float*)d_in[4];
  a.W1   = (const float*)d_in[5];
  a.b1   = (const float*)d_in[6];
  a.W2   = (const float*)d_in[7];
  // d_in[8] = b2: uniform over keys -> softmax invariant, unused
  a.Wv1  = (const float*)d_in[9];
  a.bv1  = (const float*)d_in[10];
  a.Wv2  = (const float*)d_in[11];
  a.bv2  = (const float*)d_in[12];
  a.alpha = (const float*)d_in[13];

  char* w = (char*)d_ws;
  a.Zj  = (float*)w;             w += (size_t)ROWS * D_ * 4;
  a.Zi  = (float*)w;             w += (size_t)ROWS * D_ * 4;
  a.Wimg   = (_Float16*)w;       w += (size_t)1024 * 16;
  a.probsH = (_Float16*)w;       w += (size_t)B_ * S_ * S_ * 2;
  a.HjH    = (_Float16*)w;       w += (size_t)ROWS * HDIM * 2;
  a.HiT    = (_Float16*)w;       w += (size_t)B_ * HDIM * S_ * 2;
  a.Wv1T   = (_Float16*)w;       w += (size_t)HDIM * 2 * HDIM * 2;
  a.Wv2T   = (_Float16*)w;       w += (size_t)HDIM * HDIM * 2;
  a.ctxH   = (_Float16*)w;       w += (size_t)ROWS * HDIM * 2;
  a.hidH   = (_Float16*)w;       w += (size_t)ROWS * HDIM * 2;
  a.out = (float*)d_out;

  void* params[1] = { (void*)&a };
  hipError_t e = hipLaunchCooperativeKernel(
      (const void*)mega_kernel, dim3(256), dim3(512), params, 0, stream);
  if (e != hipSuccess) {
    (void)hipGetLastError();   // clear sticky error, take fallback path
    fb_prep_kernel<<<1041, 512, 0, stream>>>(a);
    fb_pair_kernel<<<512, 512, 0, stream>>>(a);
    fb_gemm1_kernel<<<256, 512, 0, stream>>>(a);
    fb_gemm2_kernel<<<256, 512, 0, stream>>>(a);
    fb_gemm3_kernel<<<256, 512, 0, stream>>>(a);
  }
}

// Round 10
// 70.122 us; speedup vs baseline: 5.3360x; 5.3360x over previous
//
#include <hip/hip_runtime.h>
#include <math.h>

#define B_    2
#define S_    512
#define HDIM  1024
#define D_    24      // proj dim
#define M_    96      // pair-MLP hidden
#define ROWS  (B_*S_) // 1024

typedef _Float16 half8 __attribute__((ext_vector_type(8)));
typedef float    f32x4 __attribute__((ext_vector_type(4)));
typedef unsigned short ushort8 __attribute__((ext_vector_type(8)));

// ---------------------------------------------------------------------------
// cache-based 64x64 fp32->fp16 transpose (no LDS)
// ---------------------------------------------------------------------------
__device__ __forceinline__ void transpose_tile64_cache(
    const float* __restrict__ in, _Float16* __restrict__ out,
    int R, int C, int xt, int yt, int t) {
  int R0 = yt * 64, C0 = xt * 64;
  int c = t >> 2, rq = (t & 3) * 16;
  _Float16 o[16];
  const float* src = in + (size_t)(R0 + rq) * C + C0 + c;
#pragma unroll
  for (int e = 0; e < 16; ++e) o[e] = (_Float16)src[(size_t)e * C];
  _Float16* dst = out + (size_t)(C0 + c) * R + R0 + rq;
  *(ushort8*)dst = *(ushort8*)o;
  *(ushort8*)(dst + 8) = *(ushort8*)&o[8];
}

// ---------------------------------------------------------------------------
// MFMA projection, 64 rows per block (4 waves x 16 rows). P ([1024][24] fp32)
// staged inline into LDS fp16 B-fragments in two 16-step phases (32KB).
// ---------------------------------------------------------------------------
template <bool EMITH>
__device__ __forceinline__ void proj_mfma64(
    const float* __restrict__ H, const float* __restrict__ P,
    float* __restrict__ Z, _Float16* __restrict__ Himg,
    int r0, char* smem, int t) {
  const int w = t >> 6, l = t & 63;
  const int lo = l & 15, hi = l >> 4;
  const int row = r0 + w * 16 + lo;
  const float* hrow = H + (size_t)row * HDIM;
  f32x4 acc0 = {}, acc1 = {};

  for (int ph = 0; ph < 2; ++ph) {
    if (ph) __syncthreads();   // all waves done reading phase-0 fragments
    for (int q = 0; q < 8; ++q) {
      int s = t + q * 256;
      int slo = s & 15, shi = (s >> 4) & 3, snt = (s >> 6) & 1, sst = s >> 7;
      int d = snt * 16 + slo;
      half8 v = {};
      if (d < D_) {
        int k = (ph * 16 + sst) * 32 + shi * 8;
#pragma unroll
        for (int e = 0; e < 8; ++e)
          v[e] = (_Float16)P[(size_t)(k + e) * D_ + d];
      }
      *(half8*)(smem + s * 16) = v;
    }
    __syncthreads();

    for (int st = 0; st < 16; ++st) {
      int step = ph * 16 + st;
      const float* src = hrow + step * 32 + hi * 8;
      float4 v0 = *(const float4*)src;
      float4 v1 = *(const float4*)(src + 4);
      half8 a8;
      a8[0] = (_Float16)v0.x; a8[1] = (_Float16)v0.y;
      a8[2] = (_Float16)v0.z; a8[3] = (_Float16)v0.w;
      a8[4] = (_Float16)v1.x; a8[5] = (_Float16)v1.y;
      a8[6] = (_Float16)v1.z; a8[7] = (_Float16)v1.w;
      if (EMITH)
        *(half8*)(Himg + (size_t)row * HDIM + step * 32 + hi * 8) = a8;
      half8 b0 = *(const half8*)(smem + ((st * 2 + 0) * 64 + l) * 16);
      half8 b1 = *(const half8*)(smem + ((st * 2 + 1) * 64 + l) * 16);
      acc0 = __builtin_amdgcn_mfma_f32_16x16x32_f16(a8, b0, acc0, 0, 0, 0);
      acc1 = __builtin_amdgcn_mfma_f32_16x16x32_f16(a8, b1, acc1, 0, 0, 0);
    }
  }
#pragma unroll
  for (int rg = 0; rg < 4; ++rg) {
    int zr = r0 + w * 16 + hi * 4 + rg;
    Z[(size_t)zr * D_ + lo] = acc0[rg];
    if (lo < 8) Z[(size_t)zr * D_ + 16 + lo] = acc1[rg];
  }
}

// ---------------------------------------------------------------------------
// Merged prep kernel: blockIdx ranges (proven r8 layout)
//  [0,16)      : proj Zj (+ HjH emit), 64 rows per block
//  [16,32)     : proj Zi, 64 rows per block
//  [32,36)     : Wimg
//  [36,292)    : HiT 64x64 tiles
//  [292,804)   : Wv1T tiles
//  [804,1060)  : Wv2T tiles
// ---------------------------------------------------------------------------
__global__ __launch_bounds__(256) void prep_kernel(
    const float* __restrict__ Hj, const float* __restrict__ Hi,
    const float* __restrict__ pj, const float* __restrict__ pi,
    const float* __restrict__ W1, const float* __restrict__ Wv1,
    const float* __restrict__ Wv2,
    _Float16* __restrict__ HjH, _Float16* __restrict__ HiT,
    _Float16* __restrict__ Wv1T, _Float16* __restrict__ Wv2T,
    _Float16* __restrict__ Wimg, float* __restrict__ Zj,
    float* __restrict__ Zi) {
  __shared__ __attribute__((aligned(16))) char smem[32768];
  const int bid = blockIdx.x;
  const int t = threadIdx.x;

  if (bid < 16) {
    proj_mfma64<true>(Hj, pj, Zj, HjH, bid * 64, smem, t);
  } else if (bid < 32) {
    proj_mfma64<false>(Hi, pi, Zi, nullptr, (bid - 16) * 64, smem, t);
  } else if (bid < 36) {
    int c = (bid - 32) * 256 + t;   // 0..1023
    half8 v = {};
    if (c < 864) {
      int kc = c / 96, m = c - kc * 96;
#pragma unroll
      for (int e = 0; e < 8; ++e)
        v[e] = (_Float16)W1[(24 + kc * 8 + e) * M_ + m];
    }
    *(half8*)(Wimg + (size_t)c * 8) = v;
  } else if (bid < 292) {
    int id = bid - 36;
    int z = id >> 7, rem = id & 127;   // 16 x 8 tiles per batch
    transpose_tile64_cache(Hi + (size_t)z * S_ * HDIM,
                           HiT + (size_t)z * HDIM * S_,
                           S_, HDIM, rem & 15, rem >> 4, t);
  } else if (bid < 804) {
    int id = bid - 292;                // 16 x 32 tiles
    transpose_tile64_cache(Wv1, Wv1T, 2 * HDIM, HDIM, id & 15, id >> 4, t);
  } else {
    int id = bid - 804;                // 16 x 16 tiles
    transpose_tile64_cache(Wv2, Wv2T, HDIM, HDIM, id & 15, id >> 4, t);
  }
}

// ---------------------------------------------------------------------------
// Fused pair-MLP + softmax. One block per j-row (1024 blocks, 256 thr).
// ---------------------------------------------------------------------------
#define FOFFB   0                       // 10*256*16 = 40960
#define WOFFB   40960                   // 1024 chunks * 16 = 16384
#define ZOFFB   (WOFFB + 960*16)        // zero chunk
#define LOGOFFB (WOFFB + 16384)         // 512 f32 logits
#define ZJOFFB  (LOGOFFB + 2048)        // 24 f32
#define W2OFFB  (ZJOFFB + 96)           // 96 f32
#define REDOFFB (W2OFFB + 384)          // 8 f32
#define LDSB    (REDOFFB + 32)

__global__ __launch_bounds__(256) void pair_fused_kernel(
    const float* __restrict__ Zj, const float* __restrict__ Zi,
    const float* __restrict__ W1, const float* __restrict__ b1,
    const float* __restrict__ W2, const _Float16* __restrict__ Wimg,
    const float* __restrict__ mask, _Float16* __restrict__ probs) {
  __shared__ __attribute__((aligned(16))) char smem[LDSB];
  const int t = threadIdx.x;
  const int w = t >> 6, l = t & 63;
  const int lo = l & 15, hi = l >> 4;
  const int rj = blockIdx.x;
  const int b = rj >> 9;

#pragma unroll
  for (int r = 0; r < 4; ++r) {
    const _Float16* src = Wimg + (size_t)(r * 256 + w * 64 + l) * 8;
    __builtin_amdgcn_global_load_lds(
        (const __attribute__((address_space(1))) void*)src,
        (__attribute__((address_space(3))) void*)(smem + WOFFB + (r * 256 + w * 64) * 16),
        16, 0, 0);
  }
  float* zjL    = (float*)(smem + ZJOFFB);
  float* W2s    = (float*)(smem + W2OFFB);
  float* logits = (float*)(smem + LOGOFFB);
  float* red    = (float*)(smem + REDOFFB);
  if (t < D_) zjL[t] = Zj[(size_t)rj * D_ + t];
  if (t < M_) W2s[t] = W2[t];
  float aj = 0.f;
  if (t < M_) {
    aj = b1[t];
#pragma unroll
    for (int d = 0; d < D_; ++d)
      aj = fmaf(Zj[(size_t)rj * D_ + d], W1[d * M_ + t], aj);
  }
  __syncthreads();   // staging + zjL/W2s visible
  if (t < M_) {
    half8 v = {};
    v[0] = (_Float16)aj;
    *(half8*)(smem + WOFFB + (864 + t) * 16) = v;  // Aj row at K=72
  }

  half8 wf[6][3];
  float w2r[6][4];

  for (int p = 0; p < 2; ++p) {
    {
      int i = p * 256 + t;
      const float* zi = Zi + (size_t)(b * S_ + i) * D_;
      float ziv[D_];
#pragma unroll
      for (int q = 0; q < 6; ++q) {
        float4 v = ((const float4*)zi)[q];
        ziv[q * 4 + 0] = v.x; ziv[q * 4 + 1] = v.y;
        ziv[q * 4 + 2] = v.z; ziv[q * 4 + 3] = v.w;
      }
#pragma unroll
      for (int kc = 0; kc < 3; ++kc) {
        half8 v;
#pragma unroll
        for (int e = 0; e < 8; ++e) v[e] = (_Float16)ziv[kc * 8 + e];
        *(half8*)(smem + FOFFB + (kc * 256 + t) * 16) = v;
      }
#pragma unroll
      for (int kc = 0; kc < 3; ++kc) {
        half8 v;
#pragma unroll
        for (int e = 0; e < 8; ++e) {
          int d = kc * 8 + e;
          v[e] = (_Float16)(zjL[d] * ziv[d]);
        }
        *(half8*)(smem + FOFFB + ((kc + 3) * 256 + t) * 16) = v;
      }
#pragma unroll
      for (int kc = 0; kc < 3; ++kc) {
        half8 v;
#pragma unroll
        for (int e = 0; e < 8; ++e) {
          int d = kc * 8 + e;
          v[e] = (_Float16)fabsf(zjL[d] - ziv[d]);
        }
        *(half8*)(smem + FOFFB + ((kc + 6) * 256 + t) * 16) = v;
      }
      if (p == 0) {
        half8 v = {};
        v[0] = (_Float16)1.0f;
        *(half8*)(smem + FOFFB + (9 * 256 + t) * 16) = v;
      }
    }
    __syncthreads();

    if (p == 0) {
#pragma unroll
      for (int mh = 0; mh < 6; ++mh) {
#pragma unroll
        for (int ks = 0; ks < 3; ++ks) {
          int kc = ks * 4 + hi;
          int off = (kc < 10) ? (WOFFB + (kc * 96 + mh * 16 + lo) * 16) : ZOFFB;
          wf[mh][ks] = *(const half8*)(smem + off);
        }
#pragma unroll
        for (int r = 0; r < 4; ++r) w2r[mh][r] = W2s[mh * 16 + hi * 4 + r];
      }
    }

#pragma unroll
    for (int nt = 0; nt < 4; ++nt) {
      half8 ff[3];
#pragma unroll
      for (int ks = 0; ks < 3; ++ks) {
        int kc = ks * 4 + hi;
        int off = (kc < 10) ? (FOFFB + (kc * 256 + w * 64 + nt * 16 + lo) * 16) : ZOFFB;
        ff[ks] = *(const half8*)(smem + off);
      }
      f32x4 a6[6] = {};
      __builtin_amdgcn_s_setprio(1);
#pragma unroll
      for (int ks = 0; ks < 3; ++ks)
#pragma unroll
        for (int mh = 0; mh < 6; ++mh)
          a6[mh] = __builtin_amdgcn_mfma_f32_16x16x32_f16(wf[mh][ks], ff[ks], a6[mh], 0, 0, 0);
      __builtin_amdgcn_s_setprio(0);
      float part = 0.f;
#pragma unroll
      for (int mh = 0; mh < 6; ++mh)
#pragma unroll
        for (int r = 0; r < 4; ++r)
          part = fmaf(fmaxf(a6[mh][r], 0.f), w2r[mh][r], part);
      part += __shfl_xor(part, 16);
      part += __shfl_xor(part, 32);
      if (hi == 0) logits[p * 256 + w * 64 + nt * 16 + lo] = part;
    }
    __syncthreads();
  }

  float m1 = mask[b * S_ + t], m2 = mask[b * S_ + t + 256];
  float lg1 = logits[t]       + (1.0f - m1) * (-3.40282347e38f);
  float lg2 = logits[t + 256] + (1.0f - m2) * (-3.40282347e38f);
  float mx = fmaxf(lg1, lg2);
#pragma unroll
  for (int off = 32; off > 0; off >>= 1) mx = fmaxf(mx, __shfl_xor(mx, off));
  if (l == 0) red[w] = mx;
  __syncthreads();
  float rmax = fmaxf(fmaxf(red[0], red[1]), fmaxf(red[2], red[3]));
  float e1 = __expf(lg1 - rmax);
  float e2 = __expf(lg2 - rmax);
  float s = e1 + e2;
#pragma unroll
  for (int off = 32; off > 0; off >>= 1) s += __shfl_xor(s, off);
  if (l == 0) red[4 + w] = s;
  __syncthreads();
  float inv = 1.0f / (red[4] + red[5] + red[6] + red[7]);
  probs[(size_t)rj * S_ + t]       = (_Float16)(e1 * inv);
  probs[(size_t)rj * S_ + t + 256] = (_Float16)(e2 * inv);
}

// ---------------------------------------------------------------------------
// fp16 MFMA GEMM, in-block split-K/2: 512 thr = 2 groups x 4 waves.
// r4 structure with DEEPER ring: 8 x 8KB buffers per group (64KB), depth-6
// prefetch, counted vmcnt(10..0) ladder — covers ~900cy cross-XCD misses.
// ---------------------------------------------------------------------------
template <bool HASA1, bool RELU, bool FINAL, bool OUTH>
__global__ __launch_bounds__(512) void mfma_gemm_kernel(
    const _Float16* __restrict__ A0, const _Float16* __restrict__ A1,
    const _Float16* __restrict__ Bt, const float* __restrict__ bias,
    const float* __restrict__ alpha_ptr, void* __restrict__ Cout,
    int M, int N, int K0, int K1,
    long aB0, long aB1, long bB, long cB) {
  __shared__ __attribute__((aligned(16))) char smem[131072];
  const int t = threadIdx.x;
  const int w = t >> 6, l = t & 63;
  const int g = w >> 2, wq = w & 3;
  const int K = K0 + K1;
  const int KH = K >> 1;
  const int NT = KH >> 5;    // 8 / 16 / 32 here
  const int n0 = blockIdx.x * 64, m0 = blockIdx.y * 64;
  const int zb = blockIdx.z;
  const _Float16* A0b = A0 + (size_t)zb * aB0;
  const _Float16* A1b = HASA1 ? (A1 + (size_t)zb * aB1) : nullptr;
  const _Float16* Btb = Bt + (size_t)zb * bB;
  char* gls = smem + (g << 16);

  const int sr = (wq << 4) + (l >> 2);
  const int sk = ((l & 3) ^ ((l >> 3) & 3)) << 3;

  const int mq = wq >> 1, nq = wq & 1;
  int offA[2], offB[2];
#pragma unroll
  for (int i = 0; i < 2; ++i) {
    int ra = mq * 32 + i * 16 + (l & 15);
    offA[i] = ra * 64 + (((l >> 4) ^ ((ra >> 1) & 3)) << 4);
    int rb = nq * 32 + i * 16 + (l & 15);
    offB[i] = 4096 + rb * 64 + (((l >> 4) ^ ((rb >> 1) & 3)) << 4);
  }

  f32x4 acc[2][2] = {};

  auto stage = [&](int tt) {
    char* buf = gls + (tt & 7) * 8192;
    int kg = g * KH + (tt << 5) + sk;
    const _Float16* ga;
    if (HASA1 && kg >= K0) ga = A1b + (size_t)(m0 + sr) * K1 + (kg - K0);
    else                   ga = A0b + (size_t)(m0 + sr) * K0 + kg;
    __builtin_amdgcn_global_load_lds(
        (const __attribute__((address_space(1))) void*)ga,
        (__attribute__((address_space(3))) void*)(buf + (wq << 10)), 16, 0, 0);
    const _Float16* gb = Btb + (size_t)(n0 + sr) * K + kg;
    __builtin_amdgcn_global_load_lds(
        (const __attribute__((address_space(1))) void*)gb,
        (__attribute__((address_space(3))) void*)(buf + 4096 + (wq << 10)), 16, 0, 0);
  };

  stage(0);
  stage(1);
  stage(2);
  stage(3);
  stage(4);
  stage(5);

  for (int tt = 0; tt < NT; ++tt) {
    if (tt + 5 < NT)      asm volatile("s_waitcnt vmcnt(10)" ::: "memory");
    else if (tt + 4 < NT) asm volatile("s_waitcnt vmcnt(8)" ::: "memory");
    else if (tt + 3 < NT) asm volatile("s_waitcnt vmcnt(6)" ::: "memory");
    else if (tt + 2 < NT) asm volatile("s_waitcnt vmcnt(4)" ::: "memory");
    else if (tt + 1 < NT) asm volatile("s_waitcnt vmcnt(2)" ::: "memory");
    else                  asm volatile("s_waitcnt vmcnt(0)" ::: "memory");
    __builtin_amdgcn_s_barrier();
    __builtin_amdgcn_sched_barrier(0);
    const char* buf = gls + (tt & 7) * 8192;
    half8 a0 = *(const half8*)(buf + offA[0]);
    half8 a1 = *(const half8*)(buf + offA[1]);
    half8 b0 = *(const half8*)(buf + offB[0]);
    half8 b1v = *(const half8*)(buf + offB[1]);
    acc[0][0] = __builtin_amdgcn_mfma_f32_16x16x32_f16(a0, b0, acc[0][0], 0, 0, 0);
    acc[0][1] = __builtin_amdgcn_mfma_f32_16x16x32_f16(a0, b1v, acc[0][1], 0, 0, 0);
    acc[1][0] = __builtin_amdgcn_mfma_f32_16x16x32_f16(a1, b0, acc[1][0], 0, 0, 0);
    acc[1][1] = __builtin_amdgcn_mfma_f32_16x16x32_f16(a1, b1v, acc[1][1], 0, 0, 0);
    if (tt + 6 < NT) stage(tt + 6);
  }

  // cross-group K reduction through LDS (overlays group-0 ring, now dead)
  const int lr = l & 15, lq = l >> 4;
  float* redm = (float*)smem;   // [64][68]
  __syncthreads();
  if (g == 1) {
#pragma unroll
    for (int mi = 0; mi < 2; ++mi)
#pragma unroll
      for (int ni = 0; ni < 2; ++ni)
#pragma unroll
        for (int rg = 0; rg < 4; ++rg)
          redm[(mq * 32 + mi * 16 + lq * 4 + rg) * 68 + nq * 32 + ni * 16 + lr] =
              acc[mi][ni][rg];
  }
  __syncthreads();
  if (g == 0) {
    const float alpha = FINAL ? *alpha_ptr : 1.0f;
    const size_t cbase = (size_t)zb * cB;
#pragma unroll
    for (int mi = 0; mi < 2; ++mi)
#pragma unroll
      for (int ni = 0; ni < 2; ++ni) {
        int col = n0 + nq * 32 + ni * 16 + lr;
        float bv = bias ? bias[col] : 0.0f;
#pragma unroll
        for (int rg = 0; rg < 4; ++rg) {
          int row = m0 + mq * 32 + mi * 16 + lq * 4 + rg;
          float x = acc[mi][ni][rg] +
                    redm[(mq * 32 + mi * 16 + lq * 4 + rg) * 68 + nq * 32 + ni * 16 + lr] +
                    bv;
          if (RELU) x = fmaxf(x, 0.f);
          if (FINAL) x *= alpha;
          if (OUTH)
            ((_Float16*)Cout)[cbase + (size_t)row * N + col] = (_Float16)x;
          else
            ((float*)Cout)[cbase + (size_t)row * N + col] = x;
        }
      }
  }
}

// ---------------------------------------------------------------------------
extern "C" void kernel_launch(void* const* d_in, const int* in_sizes, int n_in,
                              void* d_out, int out_size, void* d_ws, size_t ws_size,
                              hipStream_t stream) {
  const float* Hj   = (const float*)d_in[0];
  const float* Hi   = (const float*)d_in[1];
  const float* mask = (const float*)d_in[2];
  const float* pj   = (const float*)d_in[3];
  const float* pi   = (const float*)d_in[4];
  const float* W1   = (const float*)d_in[5];
  const float* b1   = (const float*)d_in[6];
  const float* W2   = (const float*)d_in[7];
  // d_in[8] = b2: uniform over keys -> softmax invariant, unused
  const float* Wv1  = (const float*)d_in[9];
  const float* bv1  = (const float*)d_in[10];
  const float* Wv2  = (const float*)d_in[11];
  const float* bv2  = (const float*)d_in[12];
  const float* alpha = (const float*)d_in[13];

  char* w = (char*)d_ws;
  float* Zj  = (float*)w;            w += (size_t)ROWS * D_ * 4;
  float* Zi  = (float*)w;            w += (size_t)ROWS * D_ * 4;
  _Float16* Wimg   = (_Float16*)w;   w += (size_t)1024 * 16;
  _Float16* probsH = (_Float16*)w;   w += (size_t)B_ * S_ * S_ * 2;
  _Float16* HjH    = (_Float16*)w;   w += (size_t)ROWS * HDIM * 2;
  _Float16* HiT    = (_Float16*)w;   w += (size_t)B_ * HDIM * S_ * 2;
  _Float16* Wv1T   = (_Float16*)w;   w += (size_t)HDIM * 2 * HDIM * 2;
  _Float16* Wv2T   = (_Float16*)w;   w += (size_t)HDIM * HDIM * 2;
  _Float16* ctxH   = (_Float16*)w;   w += (size_t)ROWS * HDIM * 2;
  _Float16* hidH   = (_Float16*)w;   w += (size_t)ROWS * HDIM * 2;
  float* out = (float*)d_out;

  // all prep: projections (MFMA, inline P staging), weight images, transposes
  prep_kernel<<<1060, 256, 0, stream>>>(Hj, Hi, pj, pi, W1, Wv1, Wv2,
                                        HjH, HiT, Wv1T, Wv2T, Wimg, Zj, Zi);

  pair_fused_kernel<<<ROWS, 256, 0, stream>>>(Zj, Zi, W1, b1, W2, Wimg,
                                              mask, probsH);

  // ctx[b] = probs[b] @ Hi[b]   (M=512, N=1024, K=512) -> fp16
  mfma_gemm_kernel<false, false, false, true><<<dim3(16, 8, 2), 512, 0, stream>>>(
      probsH, nullptr, HiT, nullptr, nullptr, ctxH,
      S_, HDIM, S_, 0, (long)S_ * S_, 0, (long)HDIM * S_, (long)S_ * HDIM);
  // hidden = relu([ctx | Hj] @ Wv1 + bv1)   (M=1024, N=1024, K=2048) -> fp16
  mfma_gemm_kernel<true, true, false, true><<<dim3(16, 16, 1), 512, 0, stream>>>(
      ctxH, HjH, Wv1T, bv1, nullptr, hidH,
      ROWS, HDIM, HDIM, HDIM, 0, 0, 0, 0);
  // out = alpha * (hidden @ Wv2 + bv2)      (M=1024, N=1024, K=1024) -> fp32
  mfma_gemm_kernel<false, false, true, false><<<dim3(16, 16, 1), 512, 0, stream>>>(
      hidH, nullptr, Wv2T, bv2, alpha, out,
      ROWS, HDIM, HDIM, 0, 0, 0, 0, 0);
}

// Round 11
// 69.011 us; speedup vs baseline: 5.4219x; 1.0161x over previous
//
#include <hip/hip_runtime.h>
#include <math.h>

#define B_    2
#define S_    512
#define HDIM  1024
#define D_    24      // proj dim
#define M_    96      // pair-MLP hidden
#define ROWS  (B_*S_) // 1024

typedef _Float16 half8 __attribute__((ext_vector_type(8)));
typedef float    f32x4 __attribute__((ext_vector_type(4)));
typedef unsigned short ushort8 __attribute__((ext_vector_type(8)));

// ---------------------------------------------------------------------------
// cache-based 64x64 fp32->fp16 transpose (no LDS)
// ---------------------------------------------------------------------------
__device__ __forceinline__ void transpose_tile64_cache(
    const float* __restrict__ in, _Float16* __restrict__ out,
    int R, int C, int xt, int yt, int t) {
  int R0 = yt * 64, C0 = xt * 64;
  int c = t >> 2, rq = (t & 3) * 16;
  _Float16 o[16];
  const float* src = in + (size_t)(R0 + rq) * C + C0 + c;
#pragma unroll
  for (int e = 0; e < 16; ++e) o[e] = (_Float16)src[(size_t)e * C];
  _Float16* dst = out + (size_t)(C0 + c) * R + R0 + rq;
  *(ushort8*)dst = *(ushort8*)o;
  *(ushort8*)(dst + 8) = *(ushort8*)&o[8];
}

// ---------------------------------------------------------------------------
// MFMA projection, 64 rows per block (4 waves x 16 rows). P ([1024][24] fp32)
// staged inline into LDS fp16 B-fragments in two 16-step phases (32KB).
// ---------------------------------------------------------------------------
template <bool EMITH>
__device__ __forceinline__ void proj_mfma64(
    const float* __restrict__ H, const float* __restrict__ P,
    float* __restrict__ Z, _Float16* __restrict__ Himg,
    int r0, char* smem, int t) {
  const int w = t >> 6, l = t & 63;
  const int lo = l & 15, hi = l >> 4;
  const int row = r0 + w * 16 + lo;
  const float* hrow = H + (size_t)row * HDIM;
  f32x4 acc0 = {}, acc1 = {};

  for (int ph = 0; ph < 2; ++ph) {
    if (ph) __syncthreads();   // all waves done reading phase-0 fragments
    for (int q = 0; q < 8; ++q) {
      int s = t + q * 256;
      int slo = s & 15, shi = (s >> 4) & 3, snt = (s >> 6) & 1, sst = s >> 7;
      int d = snt * 16 + slo;
      half8 v = {};
      if (d < D_) {
        int k = (ph * 16 + sst) * 32 + shi * 8;
#pragma unroll
        for (int e = 0; e < 8; ++e)
          v[e] = (_Float16)P[(size_t)(k + e) * D_ + d];
      }
      *(half8*)(smem + s * 16) = v;
    }
    __syncthreads();

    for (int st = 0; st < 16; ++st) {
      int step = ph * 16 + st;
      const float* src = hrow + step * 32 + hi * 8;
      float4 v0 = *(const float4*)src;
      float4 v1 = *(const float4*)(src + 4);
      half8 a8;
      a8[0] = (_Float16)v0.x; a8[1] = (_Float16)v0.y;
      a8[2] = (_Float16)v0.z; a8[3] = (_Float16)v0.w;
      a8[4] = (_Float16)v1.x; a8[5] = (_Float16)v1.y;
      a8[6] = (_Float16)v1.z; a8[7] = (_Float16)v1.w;
      if (EMITH)
        *(half8*)(Himg + (size_t)row * HDIM + step * 32 + hi * 8) = a8;
      half8 b0 = *(const half8*)(smem + ((st * 2 + 0) * 64 + l) * 16);
      half8 b1 = *(const half8*)(smem + ((st * 2 + 1) * 64 + l) * 16);
      acc0 = __builtin_amdgcn_mfma_f32_16x16x32_f16(a8, b0, acc0, 0, 0, 0);
      acc1 = __builtin_amdgcn_mfma_f32_16x16x32_f16(a8, b1, acc1, 0, 0, 0);
    }
  }
#pragma unroll
  for (int rg = 0; rg < 4; ++rg) {
    int zr = r0 + w * 16 + hi * 4 + rg;
    Z[(size_t)zr * D_ + lo] = acc0[rg];
    if (lo < 8) Z[(size_t)zr * D_ + 16 + lo] = acc1[rg];
  }
}

// ---------------------------------------------------------------------------
// Merged prep kernel (proven r8 layout)
// ---------------------------------------------------------------------------
__global__ __launch_bounds__(256) void prep_kernel(
    const float* __restrict__ Hj, const float* __restrict__ Hi,
    const float* __restrict__ pj, const float* __restrict__ pi,
    const float* __restrict__ W1, const float* __restrict__ Wv1,
    const float* __restrict__ Wv2,
    _Float16* __restrict__ HjH, _Float16* __restrict__ HiT,
    _Float16* __restrict__ Wv1T, _Float16* __restrict__ Wv2T,
    _Float16* __restrict__ Wimg, float* __restrict__ Zj,
    float* __restrict__ Zi) {
  __shared__ __attribute__((aligned(16))) char smem[32768];
  const int bid = blockIdx.x;
  const int t = threadIdx.x;

  if (bid < 16) {
    proj_mfma64<true>(Hj, pj, Zj, HjH, bid * 64, smem, t);
  } else if (bid < 32) {
    proj_mfma64<false>(Hi, pi, Zi, nullptr, (bid - 16) * 64, smem, t);
  } else if (bid < 36) {
    int c = (bid - 32) * 256 + t;   // 0..1023
    half8 v = {};
    if (c < 864) {
      int kc = c / 96, m = c - kc * 96;
#pragma unroll
      for (int e = 0; e < 8; ++e)
        v[e] = (_Float16)W1[(24 + kc * 8 + e) * M_ + m];
    }
    *(half8*)(Wimg + (size_t)c * 8) = v;
  } else if (bid < 292) {
    int id = bid - 36;
    int z = id >> 7, rem = id & 127;   // 16 x 8 tiles per batch
    transpose_tile64_cache(Hi + (size_t)z * S_ * HDIM,
                           HiT + (size_t)z * HDIM * S_,
                           S_, HDIM, rem & 15, rem >> 4, t);
  } else if (bid < 804) {
    int id = bid - 292;                // 16 x 32 tiles
    transpose_tile64_cache(Wv1, Wv1T, 2 * HDIM, HDIM, id & 15, id >> 4, t);
  } else {
    int id = bid - 804;                // 16 x 16 tiles
    transpose_tile64_cache(Wv2, Wv2T, HDIM, HDIM, id & 15, id >> 4, t);
  }
}

// ---------------------------------------------------------------------------
// Fused pair-MLP + softmax. One block per j-row (1024 blocks, 256 thr).
// W-fragments loaded DIRECTLY from global Wimg into registers (no W LDS):
// LDS 43.9KB -> 3 blocks/CU. Aj row patched into the kc=9 fragment elem 0.
// ---------------------------------------------------------------------------
#define FOFFB   0                       // 10*256*16 = 40960
#define LOGOFFB 40960                   // 512 f32 logits
#define ZJOFFB  (LOGOFFB + 2048)        // 24 f32
#define W2OFFB  (ZJOFFB + 96)           // 96 f32
#define AJOFFB  (W2OFFB + 384)          // 96 f32
#define REDOFFB (AJOFFB + 384)          // 8 f32
#define ZCOFFB  (REDOFFB + 32)          // 16B zero chunk
#define LDSB    (ZCOFFB + 16)           // 43920

__global__ __launch_bounds__(256, 3) void pair_fused_kernel(
    const float* __restrict__ Zj, const float* __restrict__ Zi,
    const float* __restrict__ W1, const float* __restrict__ b1,
    const float* __restrict__ W2, const _Float16* __restrict__ Wimg,
    const float* __restrict__ mask, _Float16* __restrict__ probs) {
  __shared__ __attribute__((aligned(16))) char smem[LDSB];
  const int t = threadIdx.x;
  const int w = t >> 6, l = t & 63;
  const int lo = l & 15, hi = l >> 4;
  const int rj = blockIdx.x;
  const int b = rj >> 9;

  float* zjL    = (float*)(smem + ZJOFFB);
  float* W2s    = (float*)(smem + W2OFFB);
  float* ajL    = (float*)(smem + AJOFFB);
  float* logits = (float*)(smem + LOGOFFB);
  float* red    = (float*)(smem + REDOFFB);

  if (t < D_) zjL[t] = Zj[(size_t)rj * D_ + t];
  if (t < M_) {
    W2s[t] = W2[t];
    float aj = b1[t];
#pragma unroll
    for (int d = 0; d < D_; ++d)
      aj = fmaf(Zj[(size_t)rj * D_ + d], W1[d * M_ + t], aj);
    ajL[t] = aj;
  }
  if (t == 0) {
    half8 z = {};
    *(half8*)(smem + ZCOFFB) = z;
  }

  // W fragments: direct global loads (Wimg slots kc*96+mh*16+lo; kc>=10 zero)
  half8 wf[6][3];
#pragma unroll
  for (int mh = 0; mh < 6; ++mh)
#pragma unroll
    for (int ks = 0; ks < 3; ++ks) {
      int kc = ks * 4 + hi;
      half8 v = {};
      if (kc < 10)
        v = *(const half8*)(Wimg + (size_t)(kc * 96 + mh * 16 + lo) * 8);
      wf[mh][ks] = v;
    }

  __syncthreads();   // zjL / W2s / ajL / zero chunk visible

  // patch Aj row (K-row 72 = kc 9 elem 0; kc==9 iff ks==2 && hi==1)
  if (hi == 1) {
#pragma unroll
    for (int mh = 0; mh < 6; ++mh)
      wf[mh][2][0] = (_Float16)ajL[mh * 16 + lo];
  }
  float w2r[6][4];
#pragma unroll
  for (int mh = 0; mh < 6; ++mh)
#pragma unroll
    for (int r = 0; r < 4; ++r) w2r[mh][r] = W2s[mh * 16 + hi * 4 + r];

  for (int p = 0; p < 2; ++p) {
    // ---- feature build: thread owns key i = p*256 + t ----
    {
      int i = p * 256 + t;
      const float* zi = Zi + (size_t)(b * S_ + i) * D_;
      float ziv[D_];
#pragma unroll
      for (int q = 0; q < 6; ++q) {
        float4 v = ((const float4*)zi)[q];
        ziv[q * 4 + 0] = v.x; ziv[q * 4 + 1] = v.y;
        ziv[q * 4 + 2] = v.z; ziv[q * 4 + 3] = v.w;
      }
#pragma unroll
      for (int kc = 0; kc < 3; ++kc) {
        half8 v;
#pragma unroll
        for (int e = 0; e < 8; ++e) v[e] = (_Float16)ziv[kc * 8 + e];
        *(half8*)(smem + FOFFB + (kc * 256 + t) * 16) = v;
      }
#pragma unroll
      for (int kc = 0; kc < 3; ++kc) {
        half8 v;
#pragma unroll
        for (int e = 0; e < 8; ++e) {
          int d = kc * 8 + e;
          v[e] = (_Float16)(zjL[d] * ziv[d]);
        }
        *(half8*)(smem + FOFFB + ((kc + 3) * 256 + t) * 16) = v;
      }
#pragma unroll
      for (int kc = 0; kc < 3; ++kc) {
        half8 v;
#pragma unroll
        for (int e = 0; e < 8; ++e) {
          int d = kc * 8 + e;
          v[e] = (_Float16)fabsf(zjL[d] - ziv[d]);
        }
        *(half8*)(smem + FOFFB + ((kc + 6) * 256 + t) * 16) = v;
      }
      if (p == 0) {
        half8 v = {};
        v[0] = (_Float16)1.0f;
        *(half8*)(smem + FOFFB + (9 * 256 + t) * 16) = v;
      }
    }
    __syncthreads();

    // ---- MFMA: wave w owns keys w*64 .. w*64+63 (4 N-tiles) ----
#pragma unroll
    for (int nt = 0; nt < 4; ++nt) {
      half8 ff[3];
#pragma unroll
      for (int ks = 0; ks < 3; ++ks) {
        int kc = ks * 4 + hi;
        int off = (kc < 10) ? (FOFFB + (kc * 256 + w * 64 + nt * 16 + lo) * 16) : ZCOFFB;
        ff[ks] = *(const half8*)(smem + off);
      }
      f32x4 a6[6] = {};
      __builtin_amdgcn_s_setprio(1);
#pragma unroll
      for (int ks = 0; ks < 3; ++ks)
#pragma unroll
        for (int mh = 0; mh < 6; ++mh)
          a6[mh] = __builtin_amdgcn_mfma_f32_16x16x32_f16(wf[mh][ks], ff[ks], a6[mh], 0, 0, 0);
      __builtin_amdgcn_s_setprio(0);
      float part = 0.f;
#pragma unroll
      for (int mh = 0; mh < 6; ++mh)
#pragma unroll
        for (int r = 0; r < 4; ++r)
          part = fmaf(fmaxf(a6[mh][r], 0.f), w2r[mh][r], part);
      part += __shfl_xor(part, 16);
      part += __shfl_xor(part, 32);
      if (hi == 0) logits[p * 256 + w * 64 + nt * 16 + lo] = part;
    }
    __syncthreads();
  }

  // ---- masked softmax over 512 keys (b2 dropped: shift-invariant) ----
  float m1 = mask[b * S_ + t], m2 = mask[b * S_ + t + 256];
  float lg1 = logits[t]       + (1.0f - m1) * (-3.40282347e38f);
  float lg2 = logits[t + 256] + (1.0f - m2) * (-3.40282347e38f);
  float mx = fmaxf(lg1, lg2);
#pragma unroll
  for (int off = 32; off > 0; off >>= 1) mx = fmaxf(mx, __shfl_xor(mx, off));
  if (l == 0) red[w] = mx;
  __syncthreads();
  float rmax = fmaxf(fmaxf(red[0], red[1]), fmaxf(red[2], red[3]));
  float e1 = __expf(lg1 - rmax);
  float e2 = __expf(lg2 - rmax);
  float s = e1 + e2;
#pragma unroll
  for (int off = 32; off > 0; off >>= 1) s += __shfl_xor(s, off);
  if (l == 0) red[4 + w] = s;
  __syncthreads();
  float inv = 1.0f / (red[4] + red[5] + red[6] + red[7]);
  probs[(size_t)rj * S_ + t]       = (_Float16)(e1 * inv);
  probs[(size_t)rj * S_ + t + 256] = (_Float16)(e2 * inv);
}

// ---------------------------------------------------------------------------
// fp16 MFMA GEMM, in-block split-K/2: 512 thr = 2 groups x 4 waves.
// r8-proven config (4 x 8KB ring, depth-3, vmcnt 4/2/0). SWZ: XCD-chunked
// bijective blockIdx swizzle for z=1 256-block grids (B-panel L2 locality).
// ---------------------------------------------------------------------------
template <bool SWZ, bool HASA1, bool RELU, bool FINAL, bool OUTH>
__global__ __launch_bounds__(512) void mfma_gemm_kernel(
    const _Float16* __restrict__ A0, const _Float16* __restrict__ A1,
    const _Float16* __restrict__ Bt, const float* __restrict__ bias,
    const float* __restrict__ alpha_ptr, void* __restrict__ Cout,
    int M, int N, int K0, int K1,
    long aB0, long aB1, long bB, long cB) {
  __shared__ __attribute__((aligned(16))) char smem[65536];
  const int t = threadIdx.x;
  const int w = t >> 6, l = t & 63;
  const int g = w >> 2, wq = w & 3;
  const int K = K0 + K1;
  const int KH = K >> 1;
  const int NT = KH >> 5;
  int n0, m0, zb;
  if (SWZ) {
    int s = (blockIdx.x & 7) * 32 + (blockIdx.x >> 3);  // XCD-chunked, bijective
    n0 = (s & 15) * 64; m0 = (s >> 4) * 64; zb = 0;
  } else {
    n0 = blockIdx.x * 64; m0 = blockIdx.y * 64; zb = blockIdx.z;
  }
  const _Float16* A0b = A0 + (size_t)zb * aB0;
  const _Float16* A1b = HASA1 ? (A1 + (size_t)zb * aB1) : nullptr;
  const _Float16* Btb = Bt + (size_t)zb * bB;
  char* gls = smem + (g << 15);

  const int sr = (wq << 4) + (l >> 2);
  const int sk = ((l & 3) ^ ((l >> 3) & 3)) << 3;

  const int mq = wq >> 1, nq = wq & 1;
  int offA[2], offB[2];
#pragma unroll
  for (int i = 0; i < 2; ++i) {
    int ra = mq * 32 + i * 16 + (l & 15);
    offA[i] = ra * 64 + (((l >> 4) ^ ((ra >> 1) & 3)) << 4);
    int rb = nq * 32 + i * 16 + (l & 15);
    offB[i] = 4096 + rb * 64 + (((l >> 4) ^ ((rb >> 1) & 3)) << 4);
  }

  f32x4 acc[2][2] = {};

  auto stage = [&](int tt) {
    char* buf = gls + (tt & 3) * 8192;
    int kg = g * KH + (tt << 5) + sk;
    const _Float16* ga;
    if (HASA1 && kg >= K0) ga = A1b + (size_t)(m0 + sr) * K1 + (kg - K0);
    else                   ga = A0b + (size_t)(m0 + sr) * K0 + kg;
    __builtin_amdgcn_global_load_lds(
        (const __attribute__((address_space(1))) void*)ga,
        (__attribute__((address_space(3))) void*)(buf + (wq << 10)), 16, 0, 0);
    const _Float16* gb = Btb + (size_t)(n0 + sr) * K + kg;
    __builtin_amdgcn_global_load_lds(
        (const __attribute__((address_space(1))) void*)gb,
        (__attribute__((address_space(3))) void*)(buf + 4096 + (wq << 10)), 16, 0, 0);
  };

  stage(0);
  stage(1);
  stage(2);

  for (int tt = 0; tt < NT; ++tt) {
    if (tt + 2 < NT)      asm volatile("s_waitcnt vmcnt(4)" ::: "memory");
    else if (tt + 1 < NT) asm volatile("s_waitcnt vmcnt(2)" ::: "memory");
    else                  asm volatile("s_waitcnt vmcnt(0)" ::: "memory");
    __builtin_amdgcn_s_barrier();
    __builtin_amdgcn_sched_barrier(0);
    const char* buf = gls + (tt & 3) * 8192;
    half8 a0 = *(const half8*)(buf + offA[0]);
    half8 a1 = *(const half8*)(buf + offA[1]);
    half8 b0 = *(const half8*)(buf + offB[0]);
    half8 b1v = *(const half8*)(buf + offB[1]);
    acc[0][0] = __builtin_amdgcn_mfma_f32_16x16x32_f16(a0, b0, acc[0][0], 0, 0, 0);
    acc[0][1] = __builtin_amdgcn_mfma_f32_16x16x32_f16(a0, b1v, acc[0][1], 0, 0, 0);
    acc[1][0] = __builtin_amdgcn_mfma_f32_16x16x32_f16(a1, b0, acc[1][0], 0, 0, 0);
    acc[1][1] = __builtin_amdgcn_mfma_f32_16x16x32_f16(a1, b1v, acc[1][1], 0, 0, 0);
    if (tt + 3 < NT) stage(tt + 3);
  }

  // cross-group K reduction through LDS (overlays group-0 ring, now dead)
  const int lr = l & 15, lq = l >> 4;
  float* redm = (float*)smem;   // [64][68]
  __syncthreads();
  if (g == 1) {
#pragma unroll
    for (int mi = 0; mi < 2; ++mi)
#pragma unroll
      for (int ni = 0; ni < 2; ++ni)
#pragma unroll
        for (int rg = 0; rg < 4; ++rg)
          redm[(mq * 32 + mi * 16 + lq * 4 + rg) * 68 + nq * 32 + ni * 16 + lr] =
              acc[mi][ni][rg];
  }
  __syncthreads();
  if (g == 0) {
    const float alpha = FINAL ? *alpha_ptr : 1.0f;
    const size_t cbase = (size_t)zb * cB;
#pragma unroll
    for (int mi = 0; mi < 2; ++mi)
#pragma unroll
      for (int ni = 0; ni < 2; ++ni) {
        int col = n0 + nq * 32 + ni * 16 + lr;
        float bv = bias ? bias[col] : 0.0f;
#pragma unroll
        for (int rg = 0; rg < 4; ++rg) {
          int row = m0 + mq * 32 + mi * 16 + lq * 4 + rg;
          float x = acc[mi][ni][rg] +
                    redm[(mq * 32 + mi * 16 + lq * 4 + rg) * 68 + nq * 32 + ni * 16 + lr] +
                    bv;
          if (RELU) x = fmaxf(x, 0.f);
          if (FINAL) x *= alpha;
          if (OUTH)
            ((_Float16*)Cout)[cbase + (size_t)row * N + col] = (_Float16)x;
          else
            ((float*)Cout)[cbase + (size_t)row * N + col] = x;
        }
      }
  }
}

// ---------------------------------------------------------------------------
extern "C" void kernel_launch(void* const* d_in, const int* in_sizes, int n_in,
                              void* d_out, int out_size, void* d_ws, size_t ws_size,
                              hipStream_t stream) {
  const float* Hj   = (const float*)d_in[0];
  const float* Hi   = (const float*)d_in[1];
  const float* mask = (const float*)d_in[2];
  const float* pj   = (const float*)d_in[3];
  const float* pi   = (const float*)d_in[4];
  const float* W1   = (const float*)d_in[5];
  const float* b1   = (const float*)d_in[6];
  const float* W2   = (const float*)d_in[7];
  // d_in[8] = b2: uniform over keys -> softmax invariant, unused
  const float* Wv1  = (const float*)d_in[9];
  const float* bv1  = (const float*)d_in[10];
  const float* Wv2  = (const float*)d_in[11];
  const float* bv2  = (const float*)d_in[12];
  const float* alpha = (const float*)d_in[13];

  char* w = (char*)d_ws;
  float* Zj  = (float*)w;            w += (size_t)ROWS * D_ * 4;
  float* Zi  = (float*)w;            w += (size_t)ROWS * D_ * 4;
  _Float16* Wimg   = (_Float16*)w;   w += (size_t)1024 * 16;
  _Float16* probsH = (_Float16*)w;   w += (size_t)B_ * S_ * S_ * 2;
  _Float16* HjH    = (_Float16*)w;   w += (size_t)ROWS * HDIM * 2;
  _Float16* HiT    = (_Float16*)w;   w += (size_t)B_ * HDIM * S_ * 2;
  _Float16* Wv1T   = (_Float16*)w;   w += (size_t)HDIM * 2 * HDIM * 2;
  _Float16* Wv2T   = (_Float16*)w;   w += (size_t)HDIM * HDIM * 2;
  _Float16* ctxH   = (_Float16*)w;   w += (size_t)ROWS * HDIM * 2;
  _Float16* hidH   = (_Float16*)w;   w += (size_t)ROWS * HDIM * 2;
  float* out = (float*)d_out;

  // all prep: projections (MFMA, inline P staging), weight images, transposes
  prep_kernel<<<1060, 256, 0, stream>>>(Hj, Hi, pj, pi, W1, Wv1, Wv2,
                                        HjH, HiT, Wv1T, Wv2T, Wimg, Zj, Zi);

  pair_fused_kernel<<<ROWS, 256, 0, stream>>>(Zj, Zi, W1, b1, W2, Wimg,
                                              mask, probsH);

  // ctx[b] = probs[b] @ Hi[b]   (M=512, N=1024, K=512) -> fp16
  mfma_gemm_kernel<false, false, false, false, true><<<dim3(16, 8, 2), 512, 0, stream>>>(
      probsH, nullptr, HiT, nullptr, nullptr, ctxH,
      S_, HDIM, S_, 0, (long)S_ * S_, 0, (long)HDIM * S_, (long)S_ * HDIM);
  // hidden = relu([ctx | Hj] @ Wv1 + bv1)   (M=1024, N=1024, K=2048) -> fp16
  mfma_gemm_kernel<true, true, true, false, true><<<dim3(256), 512, 0, stream>>>(
      ctxH, HjH, Wv1T, bv1, nullptr, hidH,
      ROWS, HDIM, HDIM, HDIM, 0, 0, 0, 0);
  // out = alpha * (hidden @ Wv2 + bv2)      (M=1024, N=1024, K=1024) -> fp32
  mfma_gemm_kernel<true, false, false, true, false><<<dim3(256), 512, 0, stream>>>(
      hidH, nullptr, Wv2T, bv2, alpha, out,
      ROWS, HDIM, HDIM, 0, 0, 0, 0, 0);
}

// Round 12
// 65.181 us; speedup vs baseline: 5.7405x; 1.0588x over previous
//
#include <hip/hip_runtime.h>
#include <math.h>

#define B_    2
#define S_    512
#define HDIM  1024
#define D_    24      // proj dim
#define M_    96      // pair-MLP hidden
#define ROWS  (B_*S_) // 1024

typedef _Float16 half8 __attribute__((ext_vector_type(8)));
typedef float    f32x4 __attribute__((ext_vector_type(4)));
typedef unsigned short ushort8 __attribute__((ext_vector_type(8)));

// ---------------------------------------------------------------------------
// cache-based 64x64 fp32->fp16 transpose (no LDS)
// ---------------------------------------------------------------------------
__device__ __forceinline__ void transpose_tile64_cache(
    const float* __restrict__ in, _Float16* __restrict__ out,
    int R, int C, int xt, int yt, int t) {
  int R0 = yt * 64, C0 = xt * 64;
  int c = t >> 2, rq = (t & 3) * 16;
  _Float16 o[16];
  const float* src = in + (size_t)(R0 + rq) * C + C0 + c;
#pragma unroll
  for (int e = 0; e < 16; ++e) o[e] = (_Float16)src[(size_t)e * C];
  _Float16* dst = out + (size_t)(C0 + c) * R + R0 + rq;
  *(ushort8*)dst = *(ushort8*)o;
  *(ushort8*)(dst + 8) = *(ushort8*)&o[8];
}

// ---------------------------------------------------------------------------
// MFMA projection, 64 rows per block (4 waves x 16 rows). P ([1024][24] fp32)
// staged inline into LDS fp16 B-fragments in two 16-step phases (32KB).
// Emits fp16 image of H rows (free: same bytes already in registers).
// ---------------------------------------------------------------------------
__device__ __forceinline__ void proj_mfma64(
    const float* __restrict__ H, const float* __restrict__ P,
    float* __restrict__ Z, _Float16* __restrict__ Himg,
    int r0, char* smem, int t) {
  const int w = t >> 6, l = t & 63;
  const int lo = l & 15, hi = l >> 4;
  const int row = r0 + w * 16 + lo;
  const float* hrow = H + (size_t)row * HDIM;
  f32x4 acc0 = {}, acc1 = {};

  for (int ph = 0; ph < 2; ++ph) {
    if (ph) __syncthreads();   // all waves done reading phase-0 fragments
    for (int q = 0; q < 8; ++q) {
      int s = t + q * 256;
      int slo = s & 15, shi = (s >> 4) & 3, snt = (s >> 6) & 1, sst = s >> 7;
      int d = snt * 16 + slo;
      half8 v = {};
      if (d < D_) {
        int k = (ph * 16 + sst) * 32 + shi * 8;
#pragma unroll
        for (int e = 0; e < 8; ++e)
          v[e] = (_Float16)P[(size_t)(k + e) * D_ + d];
      }
      *(half8*)(smem + s * 16) = v;
    }
    __syncthreads();

    for (int st = 0; st < 16; ++st) {
      int step = ph * 16 + st;
      const float* src = hrow + step * 32 + hi * 8;
      float4 v0 = *(const float4*)src;
      float4 v1 = *(const float4*)(src + 4);
      half8 a8;
      a8[0] = (_Float16)v0.x; a8[1] = (_Float16)v0.y;
      a8[2] = (_Float16)v0.z; a8[3] = (_Float16)v0.w;
      a8[4] = (_Float16)v1.x; a8[5] = (_Float16)v1.y;
      a8[6] = (_Float16)v1.z; a8[7] = (_Float16)v1.w;
      *(half8*)(Himg + (size_t)row * HDIM + step * 32 + hi * 8) = a8;
      half8 b0 = *(const half8*)(smem + ((st * 2 + 0) * 64 + l) * 16);
      half8 b1 = *(const half8*)(smem + ((st * 2 + 1) * 64 + l) * 16);
      acc0 = __builtin_amdgcn_mfma_f32_16x16x32_f16(a8, b0, acc0, 0, 0, 0);
      acc1 = __builtin_amdgcn_mfma_f32_16x16x32_f16(a8, b1, acc1, 0, 0, 0);
    }
  }
#pragma unroll
  for (int rg = 0; rg < 4; ++rg) {
    int zr = r0 + w * 16 + hi * 4 + rg;
    Z[(size_t)zr * D_ + lo] = acc0[rg];
    if (lo < 8) Z[(size_t)zr * D_ + 16 + lo] = acc1[rg];
  }
}

// ---------------------------------------------------------------------------
// Merged prep kernel: blockIdx ranges
//  [0,16)    : proj Zj + HjH emit, 64 rows per block
//  [16,32)   : proj Zi + HiH emit
//  [32,36)   : Wimg
//  [36,292)  : Wv1aT tiles (transpose of Wv1 rows 0..1023)
//  [292,548) : Wv1bT tiles (transpose of Wv1 rows 1024..2047)
//  [548,804) : Wv2T tiles
// ---------------------------------------------------------------------------
__global__ __launch_bounds__(256) void prep_kernel(
    const float* __restrict__ Hj, const float* __restrict__ Hi,
    const float* __restrict__ pj, const float* __restrict__ pi,
    const float* __restrict__ W1, const float* __restrict__ Wv1,
    const float* __restrict__ Wv2,
    _Float16* __restrict__ HjH, _Float16* __restrict__ HiH,
    _Float16* __restrict__ Wv1aT, _Float16* __restrict__ Wv1bT,
    _Float16* __restrict__ Wv2T, _Float16* __restrict__ Wimg,
    float* __restrict__ Zj, float* __restrict__ Zi) {
  __shared__ __attribute__((aligned(16))) char smem[32768];
  const int bid = blockIdx.x;
  const int t = threadIdx.x;

  if (bid < 16) {
    proj_mfma64(Hj, pj, Zj, HjH, bid * 64, smem, t);
  } else if (bid < 32) {
    proj_mfma64(Hi, pi, Zi, HiH, (bid - 16) * 64, smem, t);
  } else if (bid < 36) {
    int c = (bid - 32) * 256 + t;   // 0..1023
    half8 v = {};
    if (c < 864) {
      int kc = c / 96, m = c - kc * 96;
#pragma unroll
      for (int e = 0; e < 8; ++e)
        v[e] = (_Float16)W1[(24 + kc * 8 + e) * M_ + m];
    }
    *(half8*)(Wimg + (size_t)c * 8) = v;
  } else if (bid < 292) {
    int id = bid - 36;                 // 16 x 16 tiles
    transpose_tile64_cache(Wv1, Wv1aT, HDIM, HDIM, id & 15, id >> 4, t);
  } else if (bid < 548) {
    int id = bid - 292;
    transpose_tile64_cache(Wv1 + (size_t)HDIM * HDIM, Wv1bT, HDIM, HDIM,
                           id & 15, id >> 4, t);
  } else {
    int id = bid - 548;
    transpose_tile64_cache(Wv2, Wv2T, HDIM, HDIM, id & 15, id >> 4, t);
  }
}

// ---------------------------------------------------------------------------
// Fused pair-MLP + softmax (blocks 0..1023) AND GT GEMM (blocks 1024..1279).
// GT_b = Wv1aT @ HiH_b^T  (M=1024, N=512, K=1024) — independent of pair.
// ---------------------------------------------------------------------------
#define FOFFB   0                       // 10*256*16 = 40960
#define LOGOFFB 40960                   // 512 f32 logits
#define ZJOFFB  (LOGOFFB + 2048)        // 24 f32
#define W2OFFB  (ZJOFFB + 96)           // 96 f32
#define AJOFFB  (W2OFFB + 384)          // 96 f32
#define REDOFFB (AJOFFB + 384)          // 8 f32
#define ZCOFFB  (REDOFFB + 32)          // 16B zero chunk
#define LDSB    (ZCOFFB + 16)           // 43920

__global__ __launch_bounds__(256, 3) void pair_gt_kernel(
    const float* __restrict__ Zj, const float* __restrict__ Zi,
    const float* __restrict__ W1, const float* __restrict__ b1,
    const float* __restrict__ W2, const _Float16* __restrict__ Wimg,
    const float* __restrict__ mask, _Float16* __restrict__ probs,
    const _Float16* __restrict__ Wv1aT, const _Float16* __restrict__ HiH,
    _Float16* __restrict__ GT) {
  __shared__ __attribute__((aligned(16))) char smem[LDSB];
  const int t = threadIdx.x;
  const int w = t >> 6, l = t & 63;
  const int lo = l & 15, hi = l >> 4;

  if (blockIdx.x >= ROWS) {
    // ---------------- GT GEMM tile (256 thr, 4 waves, no split-K) ----------
    int id = blockIdx.x - ROWS;        // 0..255
    int zb = id >> 7, rem = id & 127;
    int n0 = (rem & 7) * 64, m0 = (rem >> 3) * 64;
    const _Float16* Bb = HiH + (size_t)zb * S_ * HDIM;   // [512][1024]
    _Float16* GTb = GT + (size_t)zb * HDIM * S_;         // [1024][512]

    const int sr = (w << 4) + (l >> 2);
    const int sk = ((l & 3) ^ ((l >> 3) & 3)) << 3;
    const int mq = w >> 1, nq = w & 1;
    int offA[2], offB[2];
#pragma unroll
    for (int i = 0; i < 2; ++i) {
      int ra = mq * 32 + i * 16 + (l & 15);
      offA[i] = ra * 64 + (((l >> 4) ^ ((ra >> 1) & 3)) << 4);
      int rb = nq * 32 + i * 16 + (l & 15);
      offB[i] = 4096 + rb * 64 + (((l >> 4) ^ ((rb >> 1) & 3)) << 4);
    }
    f32x4 acc[2][2] = {};

    auto stage = [&](int tt) {
      char* buf = smem + (tt & 3) * 8192;
      int kg = (tt << 5) + sk;
      const _Float16* ga = Wv1aT + (size_t)(m0 + sr) * HDIM + kg;
      __builtin_amdgcn_global_load_lds(
          (const __attribute__((address_space(1))) void*)ga,
          (__attribute__((address_space(3))) void*)(buf + (w << 10)), 16, 0, 0);
      const _Float16* gb = Bb + (size_t)(n0 + sr) * HDIM + kg;
      __builtin_amdgcn_global_load_lds(
          (const __attribute__((address_space(1))) void*)gb,
          (__attribute__((address_space(3))) void*)(buf + 4096 + (w << 10)), 16, 0, 0);
    };
    stage(0); stage(1); stage(2);
    const int NT = HDIM >> 5;   // 32
    for (int tt = 0; tt < NT; ++tt) {
      if (tt + 2 < NT)      asm volatile("s_waitcnt vmcnt(4)" ::: "memory");
      else if (tt + 1 < NT) asm volatile("s_waitcnt vmcnt(2)" ::: "memory");
      else                  asm volatile("s_waitcnt vmcnt(0)" ::: "memory");
      __builtin_amdgcn_s_barrier();
      __builtin_amdgcn_sched_barrier(0);
      const char* buf = smem + (tt & 3) * 8192;
      half8 a0 = *(const half8*)(buf + offA[0]);
      half8 a1 = *(const half8*)(buf + offA[1]);
      half8 b0 = *(const half8*)(buf + offB[0]);
      half8 b1v = *(const half8*)(buf + offB[1]);
      acc[0][0] = __builtin_amdgcn_mfma_f32_16x16x32_f16(a0, b0, acc[0][0], 0, 0, 0);
      acc[0][1] = __builtin_amdgcn_mfma_f32_16x16x32_f16(a0, b1v, acc[0][1], 0, 0, 0);
      acc[1][0] = __builtin_amdgcn_mfma_f32_16x16x32_f16(a1, b0, acc[1][0], 0, 0, 0);
      acc[1][1] = __builtin_amdgcn_mfma_f32_16x16x32_f16(a1, b1v, acc[1][1], 0, 0, 0);
      if (tt + 3 < NT) stage(tt + 3);
    }
    const int lr = l & 15, lq = l >> 4;
#pragma unroll
    for (int mi = 0; mi < 2; ++mi)
#pragma unroll
      for (int ni = 0; ni < 2; ++ni) {
        int col = n0 + nq * 32 + ni * 16 + lr;
#pragma unroll
        for (int rg = 0; rg < 4; ++rg) {
          int row = m0 + mq * 32 + mi * 16 + lq * 4 + rg;
          GTb[(size_t)row * S_ + col] = (_Float16)acc[mi][ni][rg];
        }
      }
    return;
  }

  // ---------------- pair path (r11-proven) ---------------------------------
  const int rj = blockIdx.x;
  const int b = rj >> 9;
  float* zjL    = (float*)(smem + ZJOFFB);
  float* W2s    = (float*)(smem + W2OFFB);
  float* ajL    = (float*)(smem + AJOFFB);
  float* logits = (float*)(smem + LOGOFFB);
  float* red    = (float*)(smem + REDOFFB);

  if (t < D_) zjL[t] = Zj[(size_t)rj * D_ + t];
  if (t < M_) {
    W2s[t] = W2[t];
    float aj = b1[t];
#pragma unroll
    for (int d = 0; d < D_; ++d)
      aj = fmaf(Zj[(size_t)rj * D_ + d], W1[d * M_ + t], aj);
    ajL[t] = aj;
  }
  if (t == 0) {
    half8 z = {};
    *(half8*)(smem + ZCOFFB) = z;
  }

  half8 wf[6][3];
#pragma unroll
  for (int mh = 0; mh < 6; ++mh)
#pragma unroll
    for (int ks = 0; ks < 3; ++ks) {
      int kc = ks * 4 + hi;
      half8 v = {};
      if (kc < 10)
        v = *(const half8*)(Wimg + (size_t)(kc * 96 + mh * 16 + lo) * 8);
      wf[mh][ks] = v;
    }

  __syncthreads();

  if (hi == 1) {
#pragma unroll
    for (int mh = 0; mh < 6; ++mh)
      wf[mh][2][0] = (_Float16)ajL[mh * 16 + lo];
  }
  float w2r[6][4];
#pragma unroll
  for (int mh = 0; mh < 6; ++mh)
#pragma unroll
    for (int r = 0; r < 4; ++r) w2r[mh][r] = W2s[mh * 16 + hi * 4 + r];

  for (int p = 0; p < 2; ++p) {
    {
      int i = p * 256 + t;
      const float* zi = Zi + (size_t)(b * S_ + i) * D_;
      float ziv[D_];
#pragma unroll
      for (int q = 0; q < 6; ++q) {
        float4 v = ((const float4*)zi)[q];
        ziv[q * 4 + 0] = v.x; ziv[q * 4 + 1] = v.y;
        ziv[q * 4 + 2] = v.z; ziv[q * 4 + 3] = v.w;
      }
#pragma unroll
      for (int kc = 0; kc < 3; ++kc) {
        half8 v;
#pragma unroll
        for (int e = 0; e < 8; ++e) v[e] = (_Float16)ziv[kc * 8 + e];
        *(half8*)(smem + FOFFB + (kc * 256 + t) * 16) = v;
      }
#pragma unroll
      for (int kc = 0; kc < 3; ++kc) {
        half8 v;
#pragma unroll
        for (int e = 0; e < 8; ++e) {
          int d = kc * 8 + e;
          v[e] = (_Float16)(zjL[d] * ziv[d]);
        }
        *(half8*)(smem + FOFFB + ((kc + 3) * 256 + t) * 16) = v;
      }
#pragma unroll
      for (int kc = 0; kc < 3; ++kc) {
        half8 v;
#pragma unroll
        for (int e = 0; e < 8; ++e) {
          int d = kc * 8 + e;
          v[e] = (_Float16)fabsf(zjL[d] - ziv[d]);
        }
        *(half8*)(smem + FOFFB + ((kc + 6) * 256 + t) * 16) = v;
      }
      if (p == 0) {
        half8 v = {};
        v[0] = (_Float16)1.0f;
        *(half8*)(smem + FOFFB + (9 * 256 + t) * 16) = v;
      }
    }
    __syncthreads();

#pragma unroll
    for (int nt = 0; nt < 4; ++nt) {
      half8 ff[3];
#pragma unroll
      for (int ks = 0; ks < 3; ++ks) {
        int kc = ks * 4 + hi;
        int off = (kc < 10) ? (FOFFB + (kc * 256 + w * 64 + nt * 16 + lo) * 16) : ZCOFFB;
        ff[ks] = *(const half8*)(smem + off);
      }
      f32x4 a6[6] = {};
      __builtin_amdgcn_s_setprio(1);
#pragma unroll
      for (int ks = 0; ks < 3; ++ks)
#pragma unroll
        for (int mh = 0; mh < 6; ++mh)
          a6[mh] = __builtin_amdgcn_mfma_f32_16x16x32_f16(wf[mh][ks], ff[ks], a6[mh], 0, 0, 0);
      __builtin_amdgcn_s_setprio(0);
      float part = 0.f;
#pragma unroll
      for (int mh = 0; mh < 6; ++mh)
#pragma unroll
        for (int r = 0; r < 4; ++r)
          part = fmaf(fmaxf(a6[mh][r], 0.f), w2r[mh][r], part);
      part += __shfl_xor(part, 16);
      part += __shfl_xor(part, 32);
      if (hi == 0) logits[p * 256 + w * 64 + nt * 16 + lo] = part;
    }
    __syncthreads();
  }

  float m1 = mask[b * S_ + t], m2 = mask[b * S_ + t + 256];
  float lg1 = logits[t]       + (1.0f - m1) * (-3.40282347e38f);
  float lg2 = logits[t + 256] + (1.0f - m2) * (-3.40282347e38f);
  float mx = fmaxf(lg1, lg2);
#pragma unroll
  for (int off = 32; off > 0; off >>= 1) mx = fmaxf(mx, __shfl_xor(mx, off));
  if (l == 0) red[w] = mx;
  __syncthreads();
  float rmax = fmaxf(fmaxf(red[0], red[1]), fmaxf(red[2], red[3]));
  float e1 = __expf(lg1 - rmax);
  float e2 = __expf(lg2 - rmax);
  float s = e1 + e2;
#pragma unroll
  for (int off = 32; off > 0; off >>= 1) s += __shfl_xor(s, off);
  if (l == 0) red[4 + w] = s;
  __syncthreads();
  float inv = 1.0f / (red[4] + red[5] + red[6] + red[7]);
  probs[(size_t)rj * S_ + t]       = (_Float16)(e1 * inv);
  probs[(size_t)rj * S_ + t + 256] = (_Float16)(e2 * inv);
}

// ---------------------------------------------------------------------------
// fp16 MFMA GEMM, in-block split-K/2: 512 thr = 2 groups x 4 waves.
// Concat-K on BOTH operands: A = [A0|A1], B rows = [B0_b ; B1] split at K0.
// ---------------------------------------------------------------------------
template <bool SWZ, bool HASA1, bool HASB1, bool RELU, bool FINAL, bool OUTH>
__global__ __launch_bounds__(512) void mfma_gemm_kernel(
    const _Float16* __restrict__ A0, const _Float16* __restrict__ A1,
    const _Float16* __restrict__ B0, const _Float16* __restrict__ B1,
    const float* __restrict__ bias, const float* __restrict__ alpha_ptr,
    void* __restrict__ Cout, int M, int N, int K0, int K1,
    long aB0, long aB1, long bB0, long cB) {
  __shared__ __attribute__((aligned(16))) char smem[65536];
  const int t = threadIdx.x;
  const int w = t >> 6, l = t & 63;
  const int g = w >> 2, wq = w & 3;
  const int K = K0 + K1;
  const int KH = K >> 1;
  const int NT = KH >> 5;
  int n0, m0, zb;
  if (SWZ) {
    int s = (blockIdx.x & 7) * 32 + (blockIdx.x >> 3);  // XCD-chunked, bijective
    n0 = (s & 15) * 64; m0 = (s >> 4) * 64; zb = 0;
  } else {
    n0 = blockIdx.x * 64; m0 = blockIdx.y * 64; zb = blockIdx.z;
  }
  const _Float16* A0b = A0 + (size_t)zb * aB0;
  const _Float16* A1b = HASA1 ? (A1 + (size_t)zb * aB1) : nullptr;
  const _Float16* B0b = B0 + (size_t)zb * bB0;
  const int ldB0 = HASB1 ? K0 : K;
  char* gls = smem + (g << 15);

  const int sr = (wq << 4) + (l >> 2);
  const int sk = ((l & 3) ^ ((l >> 3) & 3)) << 3;

  const int mq = wq >> 1, nq = wq & 1;
  int offA[2], offB[2];
#pragma unroll
  for (int i = 0; i < 2; ++i) {
    int ra = mq * 32 + i * 16 + (l & 15);
    offA[i] = ra * 64 + (((l >> 4) ^ ((ra >> 1) & 3)) << 4);
    int rb = nq * 32 + i * 16 + (l & 15);
    offB[i] = 4096 + rb * 64 + (((l >> 4) ^ ((rb >> 1) & 3)) << 4);
  }

  f32x4 acc[2][2] = {};

  auto stage = [&](int tt) {
    char* buf = gls + (tt & 3) * 8192;
    int kg = g * KH + (tt << 5) + sk;
    const _Float16* ga;
    if (HASA1 && kg >= K0) ga = A1b + (size_t)(m0 + sr) * K1 + (kg - K0);
    else                   ga = A0b + (size_t)(m0 + sr) * K0 + kg;
    __builtin_amdgcn_global_load_lds(
        (const __attribute__((address_space(1))) void*)ga,
        (__attribute__((address_space(3))) void*)(buf + (wq << 10)), 16, 0, 0);
    const _Float16* gb;
    if (HASB1 && kg >= K0) gb = B1 + (size_t)(n0 + sr) * K1 + (kg - K0);
    else                   gb = B0b + (size_t)(n0 + sr) * ldB0 + kg;
    __builtin_amdgcn_global_load_lds(
        (const __attribute__((address_space(1))) void*)gb,
        (__attribute__((address_space(3))) void*)(buf + 4096 + (wq << 10)), 16, 0, 0);
  };

  stage(0);
  stage(1);
  stage(2);

  for (int tt = 0; tt < NT; ++tt) {
    if (tt + 2 < NT)      asm volatile("s_waitcnt vmcnt(4)" ::: "memory");
    else if (tt + 1 < NT) asm volatile("s_waitcnt vmcnt(2)" ::: "memory");
    else                  asm volatile("s_waitcnt vmcnt(0)" ::: "memory");
    __builtin_amdgcn_s_barrier();
    __builtin_amdgcn_sched_barrier(0);
    const char* buf = gls + (tt & 3) * 8192;
    half8 a0 = *(const half8*)(buf + offA[0]);
    half8 a1 = *(const half8*)(buf + offA[1]);
    half8 b0 = *(const half8*)(buf + offB[0]);
    half8 b1v = *(const half8*)(buf + offB[1]);
    acc[0][0] = __builtin_amdgcn_mfma_f32_16x16x32_f16(a0, b0, acc[0][0], 0, 0, 0);
    acc[0][1] = __builtin_amdgcn_mfma_f32_16x16x32_f16(a0, b1v, acc[0][1], 0, 0, 0);
    acc[1][0] = __builtin_amdgcn_mfma_f32_16x16x32_f16(a1, b0, acc[1][0], 0, 0, 0);
    acc[1][1] = __builtin_amdgcn_mfma_f32_16x16x32_f16(a1, b1v, acc[1][1], 0, 0, 0);
    if (tt + 3 < NT) stage(tt + 3);
  }

  // cross-group K reduction through LDS (overlays group-0 ring, now dead)
  const int lr = l & 15, lq = l >> 4;
  float* redm = (float*)smem;   // [64][68]
  __syncthreads();
  if (g == 1) {
#pragma unroll
    for (int mi = 0; mi < 2; ++mi)
#pragma unroll
      for (int ni = 0; ni < 2; ++ni)
#pragma unroll
        for (int rg = 0; rg < 4; ++rg)
          redm[(mq * 32 + mi * 16 + lq * 4 + rg) * 68 + nq * 32 + ni * 16 + lr] =
              acc[mi][ni][rg];
  }
  __syncthreads();
  if (g == 0) {
    const float alpha = FINAL ? *alpha_ptr : 1.0f;
    const size_t cbase = (size_t)zb * cB;
#pragma unroll
    for (int mi = 0; mi < 2; ++mi)
#pragma unroll
      for (int ni = 0; ni < 2; ++ni) {
        int col = n0 + nq * 32 + ni * 16 + lr;
        float bv = bias ? bias[col] : 0.0f;
#pragma unroll
        for (int rg = 0; rg < 4; ++rg) {
          int row = m0 + mq * 32 + mi * 16 + lq * 4 + rg;
          float x = acc[mi][ni][rg] +
                    redm[(mq * 32 + mi * 16 + lq * 4 + rg) * 68 + nq * 32 + ni * 16 + lr] +
                    bv;
          if (RELU) x = fmaxf(x, 0.f);
          if (FINAL) x *= alpha;
          if (OUTH)
            ((_Float16*)Cout)[cbase + (size_t)row * N + col] = (_Float16)x;
          else
            ((float*)Cout)[cbase + (size_t)row * N + col] = x;
        }
      }
  }
}

// ---------------------------------------------------------------------------
extern "C" void kernel_launch(void* const* d_in, const int* in_sizes, int n_in,
                              void* d_out, int out_size, void* d_ws, size_t ws_size,
                              hipStream_t stream) {
  const float* Hj   = (const float*)d_in[0];
  const float* Hi   = (const float*)d_in[1];
  const float* mask = (const float*)d_in[2];
  const float* pj   = (const float*)d_in[3];
  const float* pi   = (const float*)d_in[4];
  const float* W1   = (const float*)d_in[5];
  const float* b1   = (const float*)d_in[6];
  const float* W2   = (const float*)d_in[7];
  // d_in[8] = b2: uniform over keys -> softmax invariant, unused
  const float* Wv1  = (const float*)d_in[9];
  const float* bv1  = (const float*)d_in[10];
  const float* Wv2  = (const float*)d_in[11];
  const float* bv2  = (const float*)d_in[12];
  const float* alpha = (const float*)d_in[13];

  char* w = (char*)d_ws;
  float* Zj  = (float*)w;            w += (size_t)ROWS * D_ * 4;
  float* Zi  = (float*)w;            w += (size_t)ROWS * D_ * 4;
  _Float16* Wimg   = (_Float16*)w;   w += (size_t)1024 * 16;
  _Float16* probsH = (_Float16*)w;   w += (size_t)B_ * S_ * S_ * 2;
  _Float16* HjH    = (_Float16*)w;   w += (size_t)ROWS * HDIM * 2;
  _Float16* HiH    = (_Float16*)w;   w += (size_t)ROWS * HDIM * 2;
  _Float16* Wv1aT  = (_Float16*)w;   w += (size_t)HDIM * HDIM * 2;
  _Float16* Wv1bT  = (_Float16*)w;   w += (size_t)HDIM * HDIM * 2;
  _Float16* Wv2T   = (_Float16*)w;   w += (size_t)HDIM * HDIM * 2;
  _Float16* GT     = (_Float16*)w;   w += (size_t)B_ * HDIM * S_ * 2;
  _Float16* hidH   = (_Float16*)w;   w += (size_t)ROWS * HDIM * 2;
  float* out = (float*)d_out;

  // 1) prep: projections (+fp16 images), weight images, weight transposes
  prep_kernel<<<804, 256, 0, stream>>>(Hj, Hi, pj, pi, W1, Wv1, Wv2,
                                       HjH, HiH, Wv1aT, Wv1bT, Wv2T, Wimg,
                                       Zj, Zi);

  // 2) pair-MLP+softmax (1024 blocks) + GT = Wv1aT @ HiH^T (256 blocks)
  pair_gt_kernel<<<ROWS + 256, 256, 0, stream>>>(Zj, Zi, W1, b1, W2, Wimg,
                                                 mask, probsH, Wv1aT, HiH, GT);

  // 3) hidden = relu([probs|HjH] @ [GT_b; Wv1bT]^T + bv1)  (K=1536, z=2)
  mfma_gemm_kernel<false, true, true, true, false, true>
      <<<dim3(16, 8, 2), 512, 0, stream>>>(
      probsH, HjH, GT, Wv1bT, bv1, nullptr, hidH,
      S_, HDIM, S_, HDIM,
      (long)S_ * S_, (long)S_ * HDIM, (long)HDIM * S_, (long)S_ * HDIM);

  // 4) out = alpha * (hidden @ Wv2 + bv2)   (K=1024, 256 blocks, XCD swizzle)
  mfma_gemm_kernel<true, false, false, false, true, false>
      <<<dim3(256), 512, 0, stream>>>(
      hidH, nullptr, Wv2T, nullptr, bv2, alpha, out,
      ROWS, HDIM, HDIM, 0, 0, 0, 0, 0);
}